// Round 6
// baseline (881.894 us; speedup 1.0000x reference)
//
#include <hip/hip_runtime.h>
#include <hip/hip_bf16.h>

// Problem constants
#define NB 4
#define CDIM 192
#define HEADS 8
#define CP 24
#define HH 128
#define WW 128
#define NPIX 16384  // 128*128

typedef __hip_bfloat16 bf16;
typedef __bf16 bf16x8 __attribute__((ext_vector_type(8)));
typedef float f32x4 __attribute__((ext_vector_type(4)));

__device__ __forceinline__ float toF(float v) { return v; }
__device__ __forceinline__ float toF(bf16 v) { return __bfloat162float(v); }
__device__ __forceinline__ void stF(float* p, float v) { *p = v; }
__device__ __forceinline__ void stF(bf16* p, float v) { *p = __float2bfloat16(v); }
__device__ __forceinline__ unsigned short bfbits(float v) {
    bf16 h = __float2bfloat16(v);
    return *reinterpret_cast<unsigned short*>(&h);
}
__device__ __forceinline__ float b2f(unsigned short u) {
    union { unsigned int i; float f; } c;
    c.i = ((unsigned int)u) << 16;
    return c.f;
}

// ---------------------------------------------------------------------------
// 1x1-conv GEMM via bf16 MFMA, stage-K-once variant.
// Stages the FULL K panel for a 64-px tile in LDS once, then loops over
// OCT oc-tiles of 64. Block 256 thr = 4 waves (2 oc x 2 px); wave tile
// 32 oc x 32 px. LDS row = ICPAD u16 (pad -> bank spread); XOR swizzle
// ((px>>2)&7)*8 on ic bits 3..5, applied on write and read.
// Weights bf16 [oc][IC] (+ per-batch stride w_bs), bias fp32.
// ---------------------------------------------------------------------------
template <typename TI, typename TO, int IC, int OCT, int ICPAD>
__global__ __launch_bounds__(256) void gemm1x1_allK_kernel(
    const TI* __restrict__ in0, long long bs0,
    const TI* __restrict__ in1, long long bs1, int ic_split,
    const unsigned short* __restrict__ Wbf, long long w_bs,
    const float* __restrict__ bias,
    TO* __restrict__ out, long long bs_out)
{
    __shared__ unsigned short xs[64][ICPAD];
    int tid = threadIdx.x;
    int lane = tid & 63;
    int wave = tid >> 6;
    int w_oc = wave >> 1;
    int w_px = wave & 1;
    int l15 = lane & 15;
    int lk  = lane >> 4;

    int nb = blockIdx.x * 64;
    int b  = blockIdx.z;
    const unsigned short* Wb = Wbf + (long long)b * w_bs;

    // stage IC x 64 px (4ic x 4px micro-tiles per iteration)
    for (int u = tid; u < (IC / 4) * 16; u += 256) {
        int px = (u & 15) * 4;
        int ic = (u >> 4) * 4;
        unsigned short rb[4][4];
#pragma unroll
        for (int j = 0; j < 4; ++j) {
            int ch = ic + j;
            const TI* p;
            if (ch < ic_split)
                p = in0 + (long long)b * bs0 + (long long)ch * NPIX + nb + px;
            else
                p = in1 + (long long)b * bs1 + (long long)(ch - ic_split) * NPIX + nb + px;
            if constexpr (sizeof(TI) == 4) {
                float4 v = *reinterpret_cast<const float4*>(p);
                rb[j][0] = bfbits(v.x); rb[j][1] = bfbits(v.y);
                rb[j][2] = bfbits(v.z); rb[j][3] = bfbits(v.w);
            } else {
                ushort4 v = *reinterpret_cast<const ushort4*>(p);
                rb[j][0] = v.x; rb[j][1] = v.y; rb[j][2] = v.z; rb[j][3] = v.w;
            }
        }
        int swz = ((px >> 2) & 7) * 8;
#pragma unroll
        for (int i = 0; i < 4; ++i) {
            union { unsigned short s[4]; uint2 v; } pk;
            pk.s[0] = rb[0][i]; pk.s[1] = rb[1][i];
            pk.s[2] = rb[2][i]; pk.s[3] = rb[3][i];
            *reinterpret_cast<uint2*>(&xs[px + i][ic ^ swz]) = pk.v;
        }
    }
    __syncthreads();

    int pxw = w_px * 32;
#pragma unroll 1
    for (int ot = 0; ot < OCT; ++ot) {
        int ocw = ot * 64 + w_oc * 32;
        f32x4 acc[2][2];
#pragma unroll
        for (int mi = 0; mi < 2; ++mi)
#pragma unroll
            for (int r = 0; r < 4; ++r) {
                float bz = bias[ocw + mi * 16 + lk * 4 + r];
#pragma unroll
                for (int nf = 0; nf < 2; ++nf) acc[mi][nf][r] = bz;
            }

#pragma unroll
        for (int ks = 0; ks < IC / 32; ++ks) {
            int koff = ks * 32 + lk * 8;
            bf16x8 a[2], bv[2];
#pragma unroll
            for (int mi = 0; mi < 2; ++mi)
                a[mi] = *reinterpret_cast<const bf16x8*>(
                    &Wb[(long long)(ocw + mi * 16 + l15) * IC + koff]);
#pragma unroll
            for (int nf = 0; nf < 2; ++nf) {
                int px = pxw + nf * 16 + l15;
                int swzr = ((px >> 2) & 7) * 8;
                bv[nf] = *reinterpret_cast<const bf16x8*>(&xs[px][koff ^ swzr]);
            }
#pragma unroll
            for (int mi = 0; mi < 2; ++mi)
#pragma unroll
                for (int nf = 0; nf < 2; ++nf)
                    acc[mi][nf] = __builtin_amdgcn_mfma_f32_16x16x32_bf16(
                        a[mi], bv[nf], acc[mi][nf], 0, 0, 0);
        }

#pragma unroll
        for (int mi = 0; mi < 2; ++mi)
#pragma unroll
            for (int nf = 0; nf < 2; ++nf) {
                int x = pxw + nf * 16 + l15;
#pragma unroll
                for (int r = 0; r < 4; ++r) {
                    int oc = ocw + mi * 16 + lk * 4 + r;
                    stF(&out[(long long)b * bs_out + (long long)oc * NPIX + nb + x],
                        acc[mi][nf][r]);
                }
            }
    }
}

// ---------------------------------------------------------------------------
// Grouped / depthwise 3x3 conv, pad 1 (unchanged from R5).
// ---------------------------------------------------------------------------
template <int GIN, int GOUT, int ROWS>
__global__ __launch_bounds__(256) void dwconv3x3_kernel(
    const bf16* __restrict__ in, const float* __restrict__ Wm,
    const float* __restrict__ bias, bf16* __restrict__ out, int groups)
{
    __shared__ float xs[GIN][ROWS + 2][132];
    int tid = threadIdx.x;
    int g = blockIdx.y;
    int b = blockIdx.z;
    int y0 = blockIdx.x * ROWS;
    long long bsin = (long long)groups * GIN * NPIX;
    long long bsout = (long long)groups * GOUT * NPIX;
    const bf16* inb = in + (long long)b * bsin;

    constexpr int NLOAD = GIN * (ROWS + 2) * 32;
    for (int idx = tid; idx < NLOAD; idx += 256) {
        int seg = idx & 31;
        int r = (idx >> 5) % (ROWS + 2);
        int ic = idx / (32 * (ROWS + 2));
        int yy = y0 + r - 1;
        float f0 = 0.f, f1 = 0.f, f2 = 0.f, f3 = 0.f;
        if (yy >= 0 && yy < HH) {
            ushort4 u = *reinterpret_cast<const ushort4*>(
                &inb[(long long)(g * GIN + ic) * NPIX + yy * WW + seg * 4]);
            f0 = b2f(u.x); f1 = b2f(u.y); f2 = b2f(u.z); f3 = b2f(u.w);
        }
        float* dst = &xs[ic][r][seg * 4 + 1];
        dst[0] = f0; dst[1] = f1; dst[2] = f2; dst[3] = f3;
    }
    for (int idx = tid; idx < GIN * (ROWS + 2); idx += 256) {
        int r = idx % (ROWS + 2), ic = idx / (ROWS + 2);
        xs[ic][r][0] = 0.f;
        xs[ic][r][129] = 0.f;
    }
    __syncthreads();

    constexpr int NOUT2 = GOUT * ROWS * 64;
    for (int e = tid; e < NOUT2; e += 256) {
        int px2 = (e & 63) * 2;
        int comb = e >> 6;
        int ry = comb % ROWS;
        int oc = comb / ROWS;
        int ocg = g * GOUT + oc;
        const float* wp = Wm + (long long)ocg * GIN * 9;
        float acc0 = bias[ocg];
        float acc1 = acc0;
#pragma unroll
        for (int ic = 0; ic < GIN; ++ic)
#pragma unroll
            for (int ky = 0; ky < 3; ++ky)
#pragma unroll
                for (int kx = 0; kx < 3; ++kx) {
                    float wv = wp[ic * 9 + ky * 3 + kx];
                    acc0 = fmaf(wv, xs[ic][ry + ky][px2 + kx], acc0);
                    acc1 = fmaf(wv, xs[ic][ry + ky][px2 + 1 + kx], acc1);
                }
        ushort2 st;
        st.x = bfbits(acc0);
        st.y = bfbits(acc1);
        *reinterpret_cast<ushort2*>(
            &out[(long long)b * bsout + (long long)ocg * NPIX + (y0 + ry) * WW + px2]) = st;
    }
}

// ---------------------------------------------------------------------------
// NCHW fp32 -> NHWC bf16 transpose-convert (unchanged).
// ---------------------------------------------------------------------------
__global__ __launch_bounds__(256) void nchw2nhwc_kernel(
    const float* __restrict__ in, unsigned short* __restrict__ outp)
{
    __shared__ float xs[192][65];
    int tid = threadIdx.x;
    int y = blockIdx.x >> 1;
    int x0 = (blockIdx.x & 1) * 64;
    int b = blockIdx.z;

    for (int idx = tid; idx < 192 * 64; idx += 256) {
        int ic = idx >> 6, px = idx & 63;
        xs[ic][px] = in[(((long long)b * CDIM + ic) << 14) + y * WW + x0 + px];
    }
    __syncthreads();
    for (int idx = tid; idx < 64 * 24; idx += 256) {
        int px = idx / 24, grp = idx % 24;
        union { unsigned short u[8]; uint4 v; } pk;
#pragma unroll
        for (int j = 0; j < 8; ++j) pk.u[j] = bfbits(xs[grp * 8 + j][px]);
        *reinterpret_cast<uint4*>(
            &outp[(((long long)b * HH + y) * WW + x0 + px) * CDIM + grp * 8]) = pk.v;
    }
}

// ---------------------------------------------------------------------------
// Pack kv_w (OIHW fp32) -> Wpack[oc][tap][ic] bf16. (unchanged)
// ---------------------------------------------------------------------------
__global__ __launch_bounds__(256) void pack_w_kernel(
    const float* __restrict__ w, unsigned short* __restrict__ wp)
{
    int idx = blockIdx.x * 256 + threadIdx.x;
    if (idx >= 384 * 9 * 192) return;
    int ic = idx % 192;
    int tap = (idx / 192) % 9;
    int oc = idx / (192 * 9);
    wp[idx] = bfbits(w[((long long)oc * 192 + ic) * 9 + tap]);
}

__global__ __launch_bounds__(256) void cvt_bf16_kernel(
    const float* __restrict__ src, unsigned short* __restrict__ dst, int n)
{
    int i = blockIdx.x * 256 + threadIdx.x;
    if (i < n) dst[i] = bfbits(src[i]);
}

// ---------------------------------------------------------------------------
// Dense 3x3 conv 192->384 via MFMA implicit GEMM, 64-px tiles.
// LDS xs[3][66][64] u16 (24.8 KB -> 6 blocks/CU, 24 waves). Same
// conflict-free swizzle as R5 (row stride 128 B, slot = grp ^ (col&7)).
// Block 256 = 4 waves (2 oc x 2 px); wave tile 32 oc x 32 px.
// Grid: (y*2+xhalf, 6 ocb, 4 b).
// ---------------------------------------------------------------------------
__global__ __launch_bounds__(256) void conv3x3_mfma_kernel(
    const unsigned short* __restrict__ Xbf,
    const unsigned short* __restrict__ Wpack,
    const float* __restrict__ bias,
    bf16* __restrict__ out)
{
    __shared__ unsigned short xs[3][66][64];
    int tid = threadIdx.x;
    int lane = tid & 63;
    int wave = tid >> 6;
    int w_oc = wave >> 1;
    int w_px = wave & 1;
    int l15 = lane & 15;
    int lk = lane >> 4;

    int y = blockIdx.x >> 1;
    int xstart = (blockIdx.x & 1) * 64;
    int b = blockIdx.z;
    int ocw = blockIdx.y * 64 + w_oc * 32;

    f32x4 acc[2][2];
#pragma unroll
    for (int mi = 0; mi < 2; ++mi)
#pragma unroll
        for (int r = 0; r < 4; ++r) {
            float bz = bias[ocw + mi * 16 + lk * 4 + r];
#pragma unroll
            for (int nf = 0; nf < 2; ++nf) acc[mi][nf][r] = bz;
        }

    for (int chunk = 0; chunk < 3; ++chunk) {
        int ic0 = chunk * 64;
        __syncthreads();
        for (int idx = tid; idx < 3 * 66 * 8; idx += 256) {
            int grp = idx & 7;
            int col = (idx >> 3) % 66;
            int ky = idx / (8 * 66);
            int yy = y + ky - 1;
            int xx = xstart + col - 1;
            uint4 val = make_uint4(0u, 0u, 0u, 0u);
            if (yy >= 0 && yy < HH && xx >= 0 && xx < WW)
                val = *reinterpret_cast<const uint4*>(
                    &Xbf[(((long long)b * HH + yy) * WW + xx) * CDIM + ic0 + grp * 8]);
            int slot = grp ^ (col & 7);
            *reinterpret_cast<uint4*>(&xs[ky][col][slot * 8]) = val;
        }
        __syncthreads();

#pragma unroll
        for (int tap = 0; tap < 9; ++tap) {
            int ky = tap / 3, kx = tap % 3;
#pragma unroll
            for (int ks = 0; ks < 2; ++ks) {
                bf16x8 a[2];
#pragma unroll
                for (int mi = 0; mi < 2; ++mi) {
                    int oc = ocw + mi * 16 + l15;
                    a[mi] = *reinterpret_cast<const bf16x8*>(
                        &Wpack[(((long long)oc * 9 + tap) * CDIM) + ic0 + ks * 32 + lk * 8]);
                }
                bf16x8 bv[2];
#pragma unroll
                for (int nf = 0; nf < 2; ++nf) {
                    int col = w_px * 32 + nf * 16 + l15 + kx;
                    int slot = (ks * 4 + lk) ^ (col & 7);
                    bv[nf] = *reinterpret_cast<const bf16x8*>(&xs[ky][col][slot * 8]);
                }
#pragma unroll
                for (int mi = 0; mi < 2; ++mi)
#pragma unroll
                    for (int nf = 0; nf < 2; ++nf)
                        acc[mi][nf] = __builtin_amdgcn_mfma_f32_16x16x32_bf16(
                            a[mi], bv[nf], acc[mi][nf], 0, 0, 0);
            }
        }
    }

#pragma unroll
    for (int mi = 0; mi < 2; ++mi)
#pragma unroll
        for (int nf = 0; nf < 2; ++nf) {
            int x = xstart + w_px * 32 + nf * 16 + l15;
#pragma unroll
            for (int r = 0; r < 4; ++r) {
                int oc = ocw + mi * 16 + lk * 4 + r;
                stF(&out[(((long long)b * 384 + oc) << 14) + y * WW + x], acc[mi][nf][r]);
            }
        }
}

// ---------------------------------------------------------------------------
// Reductions: per-channel sumsq q,k,v + 24x24 Gram(q,k).
// Staging now uint4-vectorized (8 bf16 per load).
// ---------------------------------------------------------------------------
__global__ __launch_bounds__(256) void reduce_qkv_kernel(
    const bf16* __restrict__ q, long long bsq,
    const bf16* __restrict__ k, long long bsk,
    const bf16* __restrict__ v, long long bsv,
    float* __restrict__ ssq, float* __restrict__ gram)
{
    __shared__ float qs[24][129], ks[24][129], vs[24][129];
    int bh = blockIdx.x;
    int b = bh >> 3, h = bh & 7;
    int n0 = blockIdx.y * 256;
    int tid = threadIdx.x;
    const unsigned short* qp = (const unsigned short*)q + (long long)b * bsq;
    const unsigned short* kp = (const unsigned short*)k + (long long)b * bsk;
    const unsigned short* vp = (const unsigned short*)v + (long long)b * bsv;

    float ag0 = 0.f, ag1 = 0.f, ag2 = 0.f;
    float accs = 0.f;
    int e0 = tid, e1 = tid + 256, e2 = tid + 512;

    for (int cc = 0; cc < 2; ++cc) {
        int nb = n0 + cc * 128;
        __syncthreads();
        for (int idx = tid; idx < 24 * 16; idx += 256) {
            int c = idx >> 4, seg = idx & 15;
            long long off = (long long)(h * CP + c) * NPIX + nb + seg * 8;
            union { uint4 u; unsigned short s[8]; } uq, uk, uv;
            uq.u = *reinterpret_cast<const uint4*>(&qp[off]);
            uk.u = *reinterpret_cast<const uint4*>(&kp[off]);
            uv.u = *reinterpret_cast<const uint4*>(&vp[off]);
#pragma unroll
            for (int j = 0; j < 8; ++j) {
                qs[c][seg * 8 + j] = b2f(uq.s[j]);
                ks[c][seg * 8 + j] = b2f(uk.s[j]);
                vs[c][seg * 8 + j] = b2f(uv.s[j]);
            }
        }
        __syncthreads();
        {
            int cq = e0 / 24, ck = e0 % 24;
            for (int i = 0; i < 128; ++i) ag0 = fmaf(qs[cq][i], ks[ck][i], ag0);
        }
        {
            int cq = e1 / 24, ck = e1 % 24;
            for (int i = 0; i < 128; ++i) ag1 = fmaf(qs[cq][i], ks[ck][i], ag1);
        }
        if (tid < 64) {
            int cq = e2 / 24, ck = e2 % 24;
            for (int i = 0; i < 128; ++i) ag2 = fmaf(qs[cq][i], ks[ck][i], ag2);
        }
        if (tid < 72) {
            int tensor = tid / 24, c = tid % 24;
            const float (*src)[129] = (tensor == 0) ? qs : (tensor == 1) ? ks : vs;
            for (int i = 0; i < 128; ++i) accs = fmaf(src[c][i], src[c][i], accs);
        }
    }
    float* gb = gram + (long long)bh * 576;
    atomicAdd(&gb[e0], ag0);
    atomicAdd(&gb[e1], ag1);
    if (tid < 64) atomicAdd(&gb[e2], ag2);
    if (tid < 72) {
        int tensor = tid / 24, c = tid % 24;
        atomicAdd(&ssq[tensor * (NB * CDIM) + b * CDIM + h * CP + c], accs);
    }
}

// ---------------------------------------------------------------------------
// Softmax + fold norms + proj into per-batch M (192x192), bf16 out.
// ---------------------------------------------------------------------------
__global__ __launch_bounds__(256) void build_M_kernel(
    const float* __restrict__ ssq, const float* __restrict__ gram,
    const float* __restrict__ temp, const float* __restrict__ proj_w,
    unsigned short* __restrict__ Mout)
{
    __shared__ float A[HEADS][CP][CP];
    __shared__ float nq[CDIM], nk[CDIM], nv[CDIM];
    int b = blockIdx.x;
    int tid = threadIdx.x;
    if (tid < CDIM) {
        nq[tid] = fmaxf(sqrtf(ssq[0 * (NB * CDIM) + b * CDIM + tid]), 1e-12f);
        nk[tid] = fmaxf(sqrtf(ssq[1 * (NB * CDIM) + b * CDIM + tid]), 1e-12f);
        nv[tid] = fmaxf(sqrtf(ssq[2 * (NB * CDIM) + b * CDIM + tid]), 1e-12f);
    }
    __syncthreads();
    if (tid < CDIM) {
        int h = tid / CP, cq = tid % CP;
        float t = temp[h];
        float row[CP];
        float m = -1e30f;
#pragma unroll
        for (int ck = 0; ck < CP; ++ck) {
            float g = gram[(long long)b * (HEADS * 576) + h * 576 + cq * CP + ck];
            g = g / (nq[h * CP + cq] * nk[h * CP + ck]) * t;
            row[ck] = g;
            m = fmaxf(m, g);
        }
        float s = 0.f;
#pragma unroll
        for (int ck = 0; ck < CP; ++ck) { row[ck] = __expf(row[ck] - m); s += row[ck]; }
        float inv = 1.f / s;
#pragma unroll
        for (int ck = 0; ck < CP; ++ck)
            A[h][cq][ck] = row[ck] * inv / nv[h * CP + ck];
    }
    __syncthreads();
    for (int e = tid; e < CDIM * CDIM; e += 256) {
        int oc = e / CDIM, d = e % CDIM;
        int h2 = d / CP, ck = d % CP;
        float acc = 0.f;
#pragma unroll
        for (int cq = 0; cq < CP; ++cq)
            acc = fmaf(proj_w[(long long)oc * CDIM + h2 * CP + cq], A[h2][cq][ck], acc);
        Mout[(long long)b * (CDIM * CDIM) + e] = bfbits(acc);
    }
}

__global__ void zero_kernel(float* __restrict__ p, int n)
{
    for (int i = blockIdx.x * 256 + threadIdx.x; i < n; i += gridDim.x * 256) p[i] = 0.f;
}

// ---------------------------------------------------------------------------
// Workspace layout identical to R5 (< 202 MB).
// ---------------------------------------------------------------------------
extern "C" void kernel_launch(void* const* d_in, const int* in_sizes, int n_in,
                              void* d_out, int out_size, void* d_ws, size_t ws_size,
                              hipStream_t stream)
{
    const float* x      = (const float*)d_in[0];
    const float* x_mask = (const float*)d_in[1];
    const float* temp   = (const float*)d_in[2];
    const float* q_w    = (const float*)d_in[3];
    const float* q_b    = (const float*)d_in[4];
    const float* qdw_w  = (const float*)d_in[5];
    const float* qdw_b  = (const float*)d_in[6];
    const float* kv_w   = (const float*)d_in[7];
    const float* kv_b   = (const float*)d_in[8];
    const float* kvdw_w = (const float*)d_in[9];
    const float* kvdw_b = (const float*)d_in[10];
    const float* newk_w = (const float*)d_in[11];
    const float* newk_b = (const float*)d_in[12];
    const float* newv_w = (const float*)d_in[13];
    const float* newv_b = (const float*)d_in[14];
    const float* proj_w = (const float*)d_in[15];
    const float* proj_b = (const float*)d_in[16];

    char* wsb = (char*)d_ws;
    bf16* A  = (bf16*)wsb;
    bf16* Bq = (bf16*)(wsb + 75497472);
    bf16* C  = (bf16*)(wsb + 150994944);
    unsigned short* qwb   = (unsigned short*)Bq;                    // 110,592
    unsigned short* nkb   = (unsigned short*)A + 25165824;          // 73,728
    unsigned short* nvb   = (unsigned short*)A + 25239552;          // 73,728
    unsigned short* Mbf   = (unsigned short*)A + 25313280;          // 147,456
    unsigned short* Wpack = (unsigned short*)C;                     // 663,552
    unsigned short* Xbf   = (unsigned short*)C + 663552;            // 12,582,912
    float* stats = (float*)(wsb + 201326592);
    float* ssq  = stats;                                            // 2304
    float* gram = ssq + 2304;                                       // 18432

    const long long N = NPIX;
    float* out = (float*)d_out;

    // stats zero + weight packs needed before S1
    zero_kernel<<<16, 256, 0, stream>>>(ssq, 2304 + 18432);
    cvt_bf16_kernel<<<432, 256, 0, stream>>>(q_w, qwb, 576 * 192);
    pack_w_kernel<<<(384 * 9 * 192 + 255) / 256, 256, 0, stream>>>(kv_w, Wpack);

    // S1: qkv1 = conv1x1(x, q_w) : 192 -> 576 (fp32 in, bf16 out) -> A
    gemm1x1_allK_kernel<float, bf16, 192, 9, 200><<<dim3(256, 1, 4), 256, 0, stream>>>(
        x, 192 * N, x, 0, 192, qwb, 0, q_b, A, 576 * N);

    // S2: qkv = grouped 3x3 (groups=192, 3in/3out) -> B
    dwconv3x3_kernel<3, 3, 8><<<dim3(16, 192, 4), 256, 0, stream>>>(
        A, qdw_w, qdw_b, Bq, 192);

    // packs into A-tail (A dead after S2) + NHWC convert into C
    cvt_bf16_kernel<<<288, 256, 0, stream>>>(newk_w, nkb, 192 * 384);
    cvt_bf16_kernel<<<288, 256, 0, stream>>>(newv_w, nvb, 192 * 384);
    nchw2nhwc_kernel<<<dim3(256, 1, 4), 256, 0, stream>>>(x_mask, Xbf);

    // S3: kv1 = dense conv3x3(x_mask) 192->384 via MFMA -> A[0:25.17M)
    conv3x3_mfma_kernel<<<dim3(256, 6, 4), 256, 0, stream>>>(Xbf, Wpack, kv_b, A);

    // S4: kv2 = depthwise 3x3 (384 groups) -> C (overwrites Wpack/Xbf, done)
    dwconv3x3_kernel<1, 1, 16><<<dim3(8, 384, 4), 256, 0, stream>>>(
        A, kvdw_w, kvdw_b, C, 384);

    // S5: k_new / v_new = conv1x1 of concat (IC=384), MFMA -> A[0:25.17M)
    bf16* k_new = A;
    bf16* v_new = A + 12582912;
    gemm1x1_allK_kernel<bf16, bf16, 384, 3, 392><<<dim3(256, 1, 4), 256, 0, stream>>>(
        Bq + 192 * N, 576 * N, C, 384 * N, 192, nkb, 0, newk_b, k_new, 192 * N);
    gemm1x1_allK_kernel<bf16, bf16, 384, 3, 392><<<dim3(256, 1, 4), 256, 0, stream>>>(
        Bq + 384 * N, 576 * N, C + 192 * N, 384 * N, 192, nvb, 0, newv_b, v_new, 192 * N);

    // S6: sumsq(q,k,v) + Gram(q,k)
    reduce_qkv_kernel<<<dim3(32, 64), 256, 0, stream>>>(
        Bq, 576 * N, k_new, 192 * N, v_new, 192 * N, ssq, gram);

    // S7: softmax + fold v-norm + proj -> per-batch M (bf16)
    build_M_kernel<<<4, 256, 0, stream>>>(ssq, gram, temp, proj_w, Mbf);

    // S8: out = M_b @ v_new + proj_b (bf16 in, fp32 out)
    gemm1x1_allK_kernel<bf16, float, 192, 3, 200><<<dim3(256, 1, 4), 256, 0, stream>>>(
        v_new, 192 * N, v_new, 0, 192, Mbf, (long long)CDIM * CDIM, proj_b, out, 192 * N);
}

// Round 7
// 612.338 us; speedup vs baseline: 1.4402x; 1.4402x over previous
//
#include <hip/hip_runtime.h>
#include <hip/hip_bf16.h>

// Problem constants
#define NB 4
#define CDIM 192
#define HEADS 8
#define CP 24
#define HH 128
#define WW 128
#define NPIX 16384  // 128*128

typedef __hip_bfloat16 bf16;
typedef __bf16 bf16x8 __attribute__((ext_vector_type(8)));
typedef float f32x4 __attribute__((ext_vector_type(4)));

__device__ __forceinline__ float toF(float v) { return v; }
__device__ __forceinline__ float toF(bf16 v) { return __bfloat162float(v); }
__device__ __forceinline__ void stF(float* p, float v) { *p = v; }
__device__ __forceinline__ void stF(bf16* p, float v) { *p = __float2bfloat16(v); }
__device__ __forceinline__ unsigned short bfbits(float v) {
    bf16 h = __float2bfloat16(v);
    return *reinterpret_cast<unsigned short*>(&h);
}
__device__ __forceinline__ float b2f(unsigned short u) {
    union { unsigned int i; float f; } c;
    c.i = ((unsigned int)u) << 16;
    return c.f;
}

// ===========================================================================
// Weight packing: lane-ordered coalesced MFMA A-operand layout.
// A-frag for mfma_f32_16x16x32_bf16: lane l (l15=l&15, lk=l>>4) holds
// elements (row=l15, k=lk*8+j). Packed so one wave A-load = 1KB contiguous.
// 1x1:  W1[oc16][ksg][lane][8],  elem = w[oc16*16+l15][ksg*32+lk*8+j]
// conv: Wc[oc16][tap][ksg][lane][8], elem = w[oc][ic][tap] of OIHW
// ===========================================================================
__global__ __launch_bounds__(256) void pack_w1x1_kernel(
    const float* __restrict__ w, unsigned short* __restrict__ wp, int OC, int IC)
{
    int e = blockIdx.x * 256 + threadIdx.x;
    if (e >= OC * IC) return;
    int j = e & 7, lane = (e >> 3) & 63, rest = e >> 9;
    int nks = IC >> 5;
    int ksg = rest % nks, oc16 = rest / nks;
    int oc = oc16 * 16 + (lane & 15);
    int ic = ksg * 32 + (lane >> 4) * 8 + j;
    wp[e] = bfbits(w[(long long)oc * IC + ic]);
}

__global__ __launch_bounds__(256) void pack_wconv_kernel(
    const float* __restrict__ w, unsigned short* __restrict__ wp)
{
    int e = blockIdx.x * 256 + threadIdx.x;
    if (e >= 384 * 9 * 192) return;
    int j = e & 7, lane = (e >> 3) & 63, rest = e >> 9;
    int ksg = rest % 6; rest /= 6;
    int tap = rest % 9;
    int oc16 = rest / 9;
    int oc = oc16 * 16 + (lane & 15);
    int ic = ksg * 32 + (lane >> 4) * 8 + j;
    wp[e] = bfbits(w[((long long)oc * 192 + ic) * 9 + tap]);
}

// ---------------------------------------------------------------------------
// 1x1-conv GEMM via bf16 MFMA, stage-K-once, coalesced packed weights.
// Block 256 thr = 4 waves (2 oc x 2 px); wave tile 32 oc x 32 px; the
// block stages IC x 64 px once and loops OCT oc-tiles of 64.
// ---------------------------------------------------------------------------
template <typename TI, typename TO, int IC, int OCT, int ICPAD>
__global__ __launch_bounds__(256) void gemm1x1_allK_kernel(
    const TI* __restrict__ in0, long long bs0,
    const TI* __restrict__ in1, long long bs1, int ic_split,
    const unsigned short* __restrict__ Wbf, long long w_bs,
    const float* __restrict__ bias,
    TO* __restrict__ out, long long bs_out)
{
    __shared__ unsigned short xs[64][ICPAD];
    int tid = threadIdx.x;
    int lane = tid & 63;
    int wave = tid >> 6;
    int w_oc = wave >> 1;
    int w_px = wave & 1;
    int l15 = lane & 15;
    int lk  = lane >> 4;
    constexpr int NKS = IC / 32;

    int nb = blockIdx.x * 64;
    int b  = blockIdx.z;
    const unsigned short* Wb = Wbf + (long long)b * w_bs;

    for (int u = tid; u < (IC / 4) * 16; u += 256) {
        int px = (u & 15) * 4;
        int ic = (u >> 4) * 4;
        unsigned short rb[4][4];
#pragma unroll
        for (int j = 0; j < 4; ++j) {
            int ch = ic + j;
            const TI* p;
            if (ch < ic_split)
                p = in0 + (long long)b * bs0 + (long long)ch * NPIX + nb + px;
            else
                p = in1 + (long long)b * bs1 + (long long)(ch - ic_split) * NPIX + nb + px;
            if constexpr (sizeof(TI) == 4) {
                float4 v = *reinterpret_cast<const float4*>(p);
                rb[j][0] = bfbits(v.x); rb[j][1] = bfbits(v.y);
                rb[j][2] = bfbits(v.z); rb[j][3] = bfbits(v.w);
            } else {
                ushort4 v = *reinterpret_cast<const ushort4*>(p);
                rb[j][0] = v.x; rb[j][1] = v.y; rb[j][2] = v.z; rb[j][3] = v.w;
            }
        }
        int swz = ((px >> 2) & 7) * 8;
#pragma unroll
        for (int i = 0; i < 4; ++i) {
            union { unsigned short s[4]; uint2 v; } pk;
            pk.s[0] = rb[0][i]; pk.s[1] = rb[1][i];
            pk.s[2] = rb[2][i]; pk.s[3] = rb[3][i];
            *reinterpret_cast<uint2*>(&xs[px + i][ic ^ swz]) = pk.v;
        }
    }
    __syncthreads();

    int pxw = w_px * 32;
#pragma unroll 1
    for (int ot = 0; ot < OCT; ++ot) {
        int ocw = ot * 64 + w_oc * 32;
        int oc16g = ot * 4 + w_oc * 2;
        f32x4 acc[2][2];
#pragma unroll
        for (int mi = 0; mi < 2; ++mi)
#pragma unroll
            for (int r = 0; r < 4; ++r) {
                float bz = bias[ocw + mi * 16 + lk * 4 + r];
#pragma unroll
                for (int nf = 0; nf < 2; ++nf) acc[mi][nf][r] = bz;
            }

#pragma unroll
        for (int ks = 0; ks < NKS; ++ks) {
            int koff = ks * 32 + lk * 8;
            bf16x8 a[2], bv[2];
#pragma unroll
            for (int mi = 0; mi < 2; ++mi)
                a[mi] = *reinterpret_cast<const bf16x8*>(
                    &Wb[((long long)(oc16g + mi) * NKS + ks) * 512 + lane * 8]);
#pragma unroll
            for (int nf = 0; nf < 2; ++nf) {
                int px = pxw + nf * 16 + l15;
                int swzr = ((px >> 2) & 7) * 8;
                bv[nf] = *reinterpret_cast<const bf16x8*>(&xs[px][koff ^ swzr]);
            }
#pragma unroll
            for (int mi = 0; mi < 2; ++mi)
#pragma unroll
                for (int nf = 0; nf < 2; ++nf)
                    acc[mi][nf] = __builtin_amdgcn_mfma_f32_16x16x32_bf16(
                        a[mi], bv[nf], acc[mi][nf], 0, 0, 0);
        }

#pragma unroll
        for (int mi = 0; mi < 2; ++mi)
#pragma unroll
            for (int nf = 0; nf < 2; ++nf) {
                int x = pxw + nf * 16 + l15;
#pragma unroll
                for (int r = 0; r < 4; ++r) {
                    int oc = ocw + mi * 16 + lk * 4 + r;
                    stF(&out[(long long)b * bs_out + (long long)oc * NPIX + nb + x],
                        acc[mi][nf][r]);
                }
            }
    }
}

// ---------------------------------------------------------------------------
// Grouped / depthwise 3x3 conv, pad 1 (unchanged).
// ---------------------------------------------------------------------------
template <int GIN, int GOUT, int ROWS>
__global__ __launch_bounds__(256) void dwconv3x3_kernel(
    const bf16* __restrict__ in, const float* __restrict__ Wm,
    const float* __restrict__ bias, bf16* __restrict__ out, int groups)
{
    __shared__ float xs[GIN][ROWS + 2][132];
    int tid = threadIdx.x;
    int g = blockIdx.y;
    int b = blockIdx.z;
    int y0 = blockIdx.x * ROWS;
    long long bsin = (long long)groups * GIN * NPIX;
    long long bsout = (long long)groups * GOUT * NPIX;
    const bf16* inb = in + (long long)b * bsin;

    constexpr int NLOAD = GIN * (ROWS + 2) * 32;
    for (int idx = tid; idx < NLOAD; idx += 256) {
        int seg = idx & 31;
        int r = (idx >> 5) % (ROWS + 2);
        int ic = idx / (32 * (ROWS + 2));
        int yy = y0 + r - 1;
        float f0 = 0.f, f1 = 0.f, f2 = 0.f, f3 = 0.f;
        if (yy >= 0 && yy < HH) {
            ushort4 u = *reinterpret_cast<const ushort4*>(
                &inb[(long long)(g * GIN + ic) * NPIX + yy * WW + seg * 4]);
            f0 = b2f(u.x); f1 = b2f(u.y); f2 = b2f(u.z); f3 = b2f(u.w);
        }
        float* dst = &xs[ic][r][seg * 4 + 1];
        dst[0] = f0; dst[1] = f1; dst[2] = f2; dst[3] = f3;
    }
    for (int idx = tid; idx < GIN * (ROWS + 2); idx += 256) {
        int r = idx % (ROWS + 2), ic = idx / (ROWS + 2);
        xs[ic][r][0] = 0.f;
        xs[ic][r][129] = 0.f;
    }
    __syncthreads();

    constexpr int NOUT2 = GOUT * ROWS * 64;
    for (int e = tid; e < NOUT2; e += 256) {
        int px2 = (e & 63) * 2;
        int comb = e >> 6;
        int ry = comb % ROWS;
        int oc = comb / ROWS;
        int ocg = g * GOUT + oc;
        const float* wp = Wm + (long long)ocg * GIN * 9;
        float acc0 = bias[ocg];
        float acc1 = acc0;
#pragma unroll
        for (int ic = 0; ic < GIN; ++ic)
#pragma unroll
            for (int ky = 0; ky < 3; ++ky)
#pragma unroll
                for (int kx = 0; kx < 3; ++kx) {
                    float wv = wp[ic * 9 + ky * 3 + kx];
                    acc0 = fmaf(wv, xs[ic][ry + ky][px2 + kx], acc0);
                    acc1 = fmaf(wv, xs[ic][ry + ky][px2 + 1 + kx], acc1);
                }
        ushort2 st;
        st.x = bfbits(acc0);
        st.y = bfbits(acc1);
        *reinterpret_cast<ushort2*>(
            &out[(long long)b * bsout + (long long)ocg * NPIX + (y0 + ry) * WW + px2]) = st;
    }
}

// ---------------------------------------------------------------------------
// NCHW fp32 -> NHWC bf16 transpose-convert (unchanged).
// ---------------------------------------------------------------------------
__global__ __launch_bounds__(256) void nchw2nhwc_kernel(
    const float* __restrict__ in, unsigned short* __restrict__ outp)
{
    __shared__ float xs[192][65];
    int tid = threadIdx.x;
    int y = blockIdx.x >> 1;
    int x0 = (blockIdx.x & 1) * 64;
    int b = blockIdx.z;

    for (int idx = tid; idx < 192 * 64; idx += 256) {
        int ic = idx >> 6, px = idx & 63;
        xs[ic][px] = in[(((long long)b * CDIM + ic) << 14) + y * WW + x0 + px];
    }
    __syncthreads();
    for (int idx = tid; idx < 64 * 24; idx += 256) {
        int px = idx / 24, grp = idx % 24;
        union { unsigned short u[8]; uint4 v; } pk;
#pragma unroll
        for (int j = 0; j < 8; ++j) pk.u[j] = bfbits(xs[grp * 8 + j][px]);
        *reinterpret_cast<uint4*>(
            &outp[(((long long)b * HH + y) * WW + x0 + px) * CDIM + grp * 8]) = pk.v;
    }
}

// ---------------------------------------------------------------------------
// Dense 3x3 conv 192->384 via MFMA implicit GEMM.
// R5 geometry: 128-px row tile, LDS xs[3][130][64] u16 (49.9 KB, 3 blk/CU),
// conflict-free XOR swizzle slot=grp^(col&7). A-loads now COALESCED from
// the lane-ordered Wc pack (1 KB contiguous per wave-load).
// Block 256 = 4 waves (2 oc x 2 px); wave tile 32 oc x 64 px (nf=4).
// ---------------------------------------------------------------------------
__global__ __launch_bounds__(256) void conv3x3_mfma_kernel(
    const unsigned short* __restrict__ Xbf,
    const unsigned short* __restrict__ Wc,
    const float* __restrict__ bias,
    bf16* __restrict__ out)
{
    __shared__ unsigned short xs[3][130][64];
    int tid = threadIdx.x;
    int lane = tid & 63;
    int wave = tid >> 6;
    int w_oc = wave >> 1;
    int w_px = wave & 1;
    int l15 = lane & 15;
    int lk = lane >> 4;

    int y = blockIdx.x;
    int b = blockIdx.z;
    int ocw = blockIdx.y * 64 + w_oc * 32;
    int oc16g = blockIdx.y * 4 + w_oc * 2;

    f32x4 acc[2][4];
#pragma unroll
    for (int mi = 0; mi < 2; ++mi)
#pragma unroll
        for (int r = 0; r < 4; ++r) {
            float bz = bias[ocw + mi * 16 + lk * 4 + r];
#pragma unroll
            for (int nf = 0; nf < 4; ++nf) acc[mi][nf][r] = bz;
        }

    for (int chunk = 0; chunk < 3; ++chunk) {
        int ic0 = chunk * 64;
        __syncthreads();
        for (int idx = tid; idx < 3 * 130 * 8; idx += 256) {
            int grp = idx & 7;
            int col = (idx >> 3) % 130;
            int ky = idx / (8 * 130);
            int yy = y + ky - 1;
            int xx = col - 1;
            uint4 val = make_uint4(0u, 0u, 0u, 0u);
            if (yy >= 0 && yy < HH && xx >= 0 && xx < WW)
                val = *reinterpret_cast<const uint4*>(
                    &Xbf[(((long long)b * HH + yy) * WW + xx) * CDIM + ic0 + grp * 8]);
            int slot = grp ^ (col & 7);
            *reinterpret_cast<uint4*>(&xs[ky][col][slot * 8]) = val;
        }
        __syncthreads();

#pragma unroll
        for (int tap = 0; tap < 9; ++tap) {
            int ky = tap / 3, kx = tap % 3;
#pragma unroll
            for (int ks = 0; ks < 2; ++ks) {
                int ksg = chunk * 2 + ks;
                bf16x8 a[2];
#pragma unroll
                for (int mi = 0; mi < 2; ++mi)
                    a[mi] = *reinterpret_cast<const bf16x8*>(
                        &Wc[((((long long)(oc16g + mi) * 9 + tap) * 6 + ksg) << 9) + lane * 8]);
                bf16x8 bv[4];
#pragma unroll
                for (int nf = 0; nf < 4; ++nf) {
                    int col = w_px * 64 + nf * 16 + l15 + kx;
                    int slot = (ks * 4 + lk) ^ (col & 7);
                    bv[nf] = *reinterpret_cast<const bf16x8*>(&xs[ky][col][slot * 8]);
                }
#pragma unroll
                for (int mi = 0; mi < 2; ++mi)
#pragma unroll
                    for (int nf = 0; nf < 4; ++nf)
                        acc[mi][nf] = __builtin_amdgcn_mfma_f32_16x16x32_bf16(
                            a[mi], bv[nf], acc[mi][nf], 0, 0, 0);
            }
        }
    }

#pragma unroll
    for (int mi = 0; mi < 2; ++mi)
#pragma unroll
        for (int nf = 0; nf < 4; ++nf) {
            int x = w_px * 64 + nf * 16 + l15;
#pragma unroll
            for (int r = 0; r < 4; ++r) {
                int oc = ocw + mi * 16 + lk * 4 + r;
                stF(&out[(((long long)b * 384 + oc) << 14) + y * WW + x], acc[mi][nf][r]);
            }
        }
}

// ---------------------------------------------------------------------------
// Reductions: per-channel sumsq q,k,v + 24x24 Gram(q,k). (unchanged)
// ---------------------------------------------------------------------------
__global__ __launch_bounds__(256) void reduce_qkv_kernel(
    const bf16* __restrict__ q, long long bsq,
    const bf16* __restrict__ k, long long bsk,
    const bf16* __restrict__ v, long long bsv,
    float* __restrict__ ssq, float* __restrict__ gram)
{
    __shared__ float qs[24][129], ks[24][129], vs[24][129];
    int bh = blockIdx.x;
    int b = bh >> 3, h = bh & 7;
    int n0 = blockIdx.y * 256;
    int tid = threadIdx.x;
    const unsigned short* qp = (const unsigned short*)q + (long long)b * bsq;
    const unsigned short* kp = (const unsigned short*)k + (long long)b * bsk;
    const unsigned short* vp = (const unsigned short*)v + (long long)b * bsv;

    float ag0 = 0.f, ag1 = 0.f, ag2 = 0.f;
    float accs = 0.f;
    int e0 = tid, e1 = tid + 256, e2 = tid + 512;

    for (int cc = 0; cc < 2; ++cc) {
        int nb = n0 + cc * 128;
        __syncthreads();
        for (int idx = tid; idx < 24 * 16; idx += 256) {
            int c = idx >> 4, seg = idx & 15;
            long long off = (long long)(h * CP + c) * NPIX + nb + seg * 8;
            union { uint4 u; unsigned short s[8]; } uq, uk, uv;
            uq.u = *reinterpret_cast<const uint4*>(&qp[off]);
            uk.u = *reinterpret_cast<const uint4*>(&kp[off]);
            uv.u = *reinterpret_cast<const uint4*>(&vp[off]);
#pragma unroll
            for (int j = 0; j < 8; ++j) {
                qs[c][seg * 8 + j] = b2f(uq.s[j]);
                ks[c][seg * 8 + j] = b2f(uk.s[j]);
                vs[c][seg * 8 + j] = b2f(uv.s[j]);
            }
        }
        __syncthreads();
        {
            int cq = e0 / 24, ck = e0 % 24;
            for (int i = 0; i < 128; ++i) ag0 = fmaf(qs[cq][i], ks[ck][i], ag0);
        }
        {
            int cq = e1 / 24, ck = e1 % 24;
            for (int i = 0; i < 128; ++i) ag1 = fmaf(qs[cq][i], ks[ck][i], ag1);
        }
        if (tid < 64) {
            int cq = e2 / 24, ck = e2 % 24;
            for (int i = 0; i < 128; ++i) ag2 = fmaf(qs[cq][i], ks[ck][i], ag2);
        }
        if (tid < 72) {
            int tensor = tid / 24, c = tid % 24;
            const float (*src)[129] = (tensor == 0) ? qs : (tensor == 1) ? ks : vs;
            for (int i = 0; i < 128; ++i) accs = fmaf(src[c][i], src[c][i], accs);
        }
    }
    float* gb = gram + (long long)bh * 576;
    atomicAdd(&gb[e0], ag0);
    atomicAdd(&gb[e1], ag1);
    if (tid < 64) atomicAdd(&gb[e2], ag2);
    if (tid < 72) {
        int tensor = tid / 24, c = tid % 24;
        atomicAdd(&ssq[tensor * (NB * CDIM) + b * CDIM + h * CP + c], accs);
    }
}

// ---------------------------------------------------------------------------
// Softmax + fold norms + proj -> per-batch M, emitted directly in the
// lane-ordered packed layout for the S8 MFMA GEMM.
// ---------------------------------------------------------------------------
__global__ __launch_bounds__(256) void build_M_kernel(
    const float* __restrict__ ssq, const float* __restrict__ gram,
    const float* __restrict__ temp, const float* __restrict__ proj_w,
    unsigned short* __restrict__ Mout)
{
    __shared__ float A[HEADS][CP][CP];
    __shared__ float nq[CDIM], nk[CDIM], nv[CDIM];
    int b = blockIdx.x;
    int tid = threadIdx.x;
    if (tid < CDIM) {
        nq[tid] = fmaxf(sqrtf(ssq[0 * (NB * CDIM) + b * CDIM + tid]), 1e-12f);
        nk[tid] = fmaxf(sqrtf(ssq[1 * (NB * CDIM) + b * CDIM + tid]), 1e-12f);
        nv[tid] = fmaxf(sqrtf(ssq[2 * (NB * CDIM) + b * CDIM + tid]), 1e-12f);
    }
    __syncthreads();
    if (tid < CDIM) {
        int h = tid / CP, cq = tid % CP;
        float t = temp[h];
        float row[CP];
        float m = -1e30f;
#pragma unroll
        for (int ck = 0; ck < CP; ++ck) {
            float g = gram[(long long)b * (HEADS * 576) + h * 576 + cq * CP + ck];
            g = g / (nq[h * CP + cq] * nk[h * CP + ck]) * t;
            row[ck] = g;
            m = fmaxf(m, g);
        }
        float s = 0.f;
#pragma unroll
        for (int ck = 0; ck < CP; ++ck) { row[ck] = __expf(row[ck] - m); s += row[ck]; }
        float inv = 1.f / s;
#pragma unroll
        for (int ck = 0; ck < CP; ++ck)
            A[h][cq][ck] = row[ck] * inv / nv[h * CP + ck];
    }
    __syncthreads();
    for (int e = tid; e < CDIM * CDIM; e += 256) {
        int oc = e / CDIM, d = e % CDIM;
        int h2 = d / CP, ck = d % CP;
        float acc = 0.f;
#pragma unroll
        for (int cq = 0; cq < CP; ++cq)
            acc = fmaf(proj_w[(long long)oc * CDIM + h2 * CP + cq], A[h2][cq][ck], acc);
        // packed layout: [oc16][ksg(6)][lane][8]
        int oc16 = oc >> 4, l15 = oc & 15;
        int ksg = d >> 5, lk = (d >> 3) & 3, j = d & 7;
        int lanep = lk * 16 + l15;
        Mout[(long long)b * (CDIM * CDIM) + (((oc16 * 6 + ksg) << 6) + lanep) * 8 + j] =
            bfbits(acc);
    }
}

__global__ void zero_kernel(float* __restrict__ p, int n)
{
    for (int i = blockIdx.x * 256 + threadIdx.x; i < n; i += gridDim.x * 256) p[i] = 0.f;
}

// ---------------------------------------------------------------------------
// Workspace layout identical to R5/R6 (< 202 MB).
// ---------------------------------------------------------------------------
extern "C" void kernel_launch(void* const* d_in, const int* in_sizes, int n_in,
                              void* d_out, int out_size, void* d_ws, size_t ws_size,
                              hipStream_t stream)
{
    const float* x      = (const float*)d_in[0];
    const float* x_mask = (const float*)d_in[1];
    const float* temp   = (const float*)d_in[2];
    const float* q_w    = (const float*)d_in[3];
    const float* q_b    = (const float*)d_in[4];
    const float* qdw_w  = (const float*)d_in[5];
    const float* qdw_b  = (const float*)d_in[6];
    const float* kv_w   = (const float*)d_in[7];
    const float* kv_b   = (const float*)d_in[8];
    const float* kvdw_w = (const float*)d_in[9];
    const float* kvdw_b = (const float*)d_in[10];
    const float* newk_w = (const float*)d_in[11];
    const float* newk_b = (const float*)d_in[12];
    const float* newv_w = (const float*)d_in[13];
    const float* newv_b = (const float*)d_in[14];
    const float* proj_w = (const float*)d_in[15];
    const float* proj_b = (const float*)d_in[16];

    char* wsb = (char*)d_ws;
    bf16* A  = (bf16*)wsb;
    bf16* Bq = (bf16*)(wsb + 75497472);
    bf16* C  = (bf16*)(wsb + 150994944);
    unsigned short* qwb   = (unsigned short*)Bq;                    // 110,592
    unsigned short* nkb   = (unsigned short*)A + 25165824;          // 73,728
    unsigned short* nvb   = (unsigned short*)A + 25239552;          // 73,728
    unsigned short* Mbf   = (unsigned short*)A + 25313280;          // 147,456
    unsigned short* Wpack = (unsigned short*)C;                     // 663,552
    unsigned short* Xbf   = (unsigned short*)C + 663552;            // 12,582,912
    float* stats = (float*)(wsb + 201326592);
    float* ssq  = stats;                                            // 2304
    float* gram = ssq + 2304;                                       // 18432

    const long long N = NPIX;
    float* out = (float*)d_out;

    // stats zero + weight packs needed before S1
    zero_kernel<<<16, 256, 0, stream>>>(ssq, 2304 + 18432);
    pack_w1x1_kernel<<<432, 256, 0, stream>>>(q_w, qwb, 576, 192);
    pack_wconv_kernel<<<(384 * 9 * 192 + 255) / 256, 256, 0, stream>>>(kv_w, Wpack);

    // S1: qkv1 = conv1x1(x, q_w) : 192 -> 576 (fp32 in, bf16 out) -> A
    gemm1x1_allK_kernel<float, bf16, 192, 9, 200><<<dim3(256, 1, 4), 256, 0, stream>>>(
        x, 192 * N, x, 0, 192, qwb, 0, q_b, A, 576 * N);

    // S2: qkv = grouped 3x3 (groups=192, 3in/3out) -> B
    dwconv3x3_kernel<3, 3, 8><<<dim3(16, 192, 4), 256, 0, stream>>>(
        A, qdw_w, qdw_b, Bq, 192);

    // packs into A-tail (A dead after S2) + NHWC convert into C
    pack_w1x1_kernel<<<288, 256, 0, stream>>>(newk_w, nkb, 192, 384);
    pack_w1x1_kernel<<<288, 256, 0, stream>>>(newv_w, nvb, 192, 384);
    nchw2nhwc_kernel<<<dim3(256, 1, 4), 256, 0, stream>>>(x_mask, Xbf);

    // S3: kv1 = dense conv3x3(x_mask) 192->384 via MFMA -> A[0:25.17M)
    conv3x3_mfma_kernel<<<dim3(128, 6, 4), 256, 0, stream>>>(Xbf, Wpack, kv_b, A);

    // S4: kv2 = depthwise 3x3 (384 groups) -> C (overwrites Wpack/Xbf, done)
    dwconv3x3_kernel<1, 1, 16><<<dim3(8, 384, 4), 256, 0, stream>>>(
        A, kvdw_w, kvdw_b, C, 384);

    // S5: k_new / v_new = conv1x1 of concat (IC=384), MFMA -> A[0:25.17M)
    bf16* k_new = A;
    bf16* v_new = A + 12582912;
    gemm1x1_allK_kernel<bf16, bf16, 384, 3, 392><<<dim3(256, 1, 4), 256, 0, stream>>>(
        Bq + 192 * N, 576 * N, C, 384 * N, 192, nkb, 0, newk_b, k_new, 192 * N);
    gemm1x1_allK_kernel<bf16, bf16, 384, 3, 392><<<dim3(256, 1, 4), 256, 0, stream>>>(
        Bq + 384 * N, 576 * N, C + 192 * N, 384 * N, 192, nvb, 0, newv_b, v_new, 192 * N);

    // S6: sumsq(q,k,v) + Gram(q,k)
    reduce_qkv_kernel<<<dim3(32, 64), 256, 0, stream>>>(
        Bq, 576 * N, k_new, 192 * N, v_new, 192 * N, ssq, gram);

    // S7: softmax + fold v-norm + proj -> per-batch M (bf16, packed layout)
    build_M_kernel<<<4, 256, 0, stream>>>(ssq, gram, temp, proj_w, Mbf);

    // S8: out = M_b @ v_new + proj_b (bf16 in, fp32 out)
    gemm1x1_allK_kernel<bf16, float, 192, 3, 200><<<dim3(256, 1, 4), 256, 0, stream>>>(
        v_new, 192 * N, v_new, 0, 192, Mbf, (long long)CDIM * CDIM, proj_b, out, 192 * N);
}

// Round 8
// 488.903 us; speedup vs baseline: 1.8038x; 1.2525x over previous
//
#include <hip/hip_runtime.h>
#include <hip/hip_bf16.h>

// Problem constants
#define NB 4
#define CDIM 192
#define HEADS 8
#define CP 24
#define HH 128
#define WW 128
#define NPIX 16384  // 128*128

typedef __hip_bfloat16 bf16;
typedef __bf16 bf16x8 __attribute__((ext_vector_type(8)));
typedef float f32x4 __attribute__((ext_vector_type(4)));

__device__ __forceinline__ float toF(float v) { return v; }
__device__ __forceinline__ float toF(bf16 v) { return __bfloat162float(v); }
__device__ __forceinline__ void stF(float* p, float v) { *p = v; }
__device__ __forceinline__ void stF(bf16* p, float v) { *p = __float2bfloat16(v); }
__device__ __forceinline__ unsigned short bfbits(float v) {
    bf16 h = __float2bfloat16(v);
    return *reinterpret_cast<unsigned short*>(&h);
}
__device__ __forceinline__ float b2f(unsigned short u) {
    union { unsigned int i; float f; } c;
    c.i = ((unsigned int)u) << 16;
    return c.f;
}

// ===========================================================================
// Weight packing: lane-ordered coalesced MFMA A-operand layout (unchanged).
// ===========================================================================
__global__ __launch_bounds__(256) void pack_w1x1_kernel(
    const float* __restrict__ w, unsigned short* __restrict__ wp, int OC, int IC)
{
    int e = blockIdx.x * 256 + threadIdx.x;
    if (e >= OC * IC) return;
    int j = e & 7, lane = (e >> 3) & 63, rest = e >> 9;
    int nks = IC >> 5;
    int ksg = rest % nks, oc16 = rest / nks;
    int oc = oc16 * 16 + (lane & 15);
    int ic = ksg * 32 + (lane >> 4) * 8 + j;
    wp[e] = bfbits(w[(long long)oc * IC + ic]);
}

__global__ __launch_bounds__(256) void pack_wconv_kernel(
    const float* __restrict__ w, unsigned short* __restrict__ wp)
{
    int e = blockIdx.x * 256 + threadIdx.x;
    if (e >= 384 * 9 * 192) return;
    int j = e & 7, lane = (e >> 3) & 63, rest = e >> 9;
    int ksg = rest % 6; rest /= 6;
    int tap = rest % 9;
    int oc16 = rest / 9;
    int oc = oc16 * 16 + (lane & 15);
    int ic = ksg * 32 + (lane >> 4) * 8 + j;
    wp[e] = bfbits(w[((long long)oc * 192 + ic) * 9 + tap]);
}

// ---------------------------------------------------------------------------
// 1x1-conv GEMM via bf16 MFMA, stage-K-once, coalesced packed weights.
// (unchanged from R7)
// ---------------------------------------------------------------------------
template <typename TI, typename TO, int IC, int OCT, int ICPAD>
__global__ __launch_bounds__(256) void gemm1x1_allK_kernel(
    const TI* __restrict__ in0, long long bs0,
    const TI* __restrict__ in1, long long bs1, int ic_split,
    const unsigned short* __restrict__ Wbf, long long w_bs,
    const float* __restrict__ bias,
    TO* __restrict__ out, long long bs_out)
{
    __shared__ unsigned short xs[64][ICPAD];
    int tid = threadIdx.x;
    int lane = tid & 63;
    int wave = tid >> 6;
    int w_oc = wave >> 1;
    int w_px = wave & 1;
    int l15 = lane & 15;
    int lk  = lane >> 4;
    constexpr int NKS = IC / 32;

    int nb = blockIdx.x * 64;
    int b  = blockIdx.z;
    const unsigned short* Wb = Wbf + (long long)b * w_bs;

    for (int u = tid; u < (IC / 4) * 16; u += 256) {
        int px = (u & 15) * 4;
        int ic = (u >> 4) * 4;
        unsigned short rb[4][4];
#pragma unroll
        for (int j = 0; j < 4; ++j) {
            int ch = ic + j;
            const TI* p;
            if (ch < ic_split)
                p = in0 + (long long)b * bs0 + (long long)ch * NPIX + nb + px;
            else
                p = in1 + (long long)b * bs1 + (long long)(ch - ic_split) * NPIX + nb + px;
            if constexpr (sizeof(TI) == 4) {
                float4 v = *reinterpret_cast<const float4*>(p);
                rb[j][0] = bfbits(v.x); rb[j][1] = bfbits(v.y);
                rb[j][2] = bfbits(v.z); rb[j][3] = bfbits(v.w);
            } else {
                ushort4 v = *reinterpret_cast<const ushort4*>(p);
                rb[j][0] = v.x; rb[j][1] = v.y; rb[j][2] = v.z; rb[j][3] = v.w;
            }
        }
        int swz = ((px >> 2) & 7) * 8;
#pragma unroll
        for (int i = 0; i < 4; ++i) {
            union { unsigned short s[4]; uint2 v; } pk;
            pk.s[0] = rb[0][i]; pk.s[1] = rb[1][i];
            pk.s[2] = rb[2][i]; pk.s[3] = rb[3][i];
            *reinterpret_cast<uint2*>(&xs[px + i][ic ^ swz]) = pk.v;
        }
    }
    __syncthreads();

    int pxw = w_px * 32;
#pragma unroll 1
    for (int ot = 0; ot < OCT; ++ot) {
        int ocw = ot * 64 + w_oc * 32;
        int oc16g = ot * 4 + w_oc * 2;
        f32x4 acc[2][2];
#pragma unroll
        for (int mi = 0; mi < 2; ++mi)
#pragma unroll
            for (int r = 0; r < 4; ++r) {
                float bz = bias[ocw + mi * 16 + lk * 4 + r];
#pragma unroll
                for (int nf = 0; nf < 2; ++nf) acc[mi][nf][r] = bz;
            }

#pragma unroll
        for (int ks = 0; ks < NKS; ++ks) {
            int koff = ks * 32 + lk * 8;
            bf16x8 a[2], bv[2];
#pragma unroll
            for (int mi = 0; mi < 2; ++mi)
                a[mi] = *reinterpret_cast<const bf16x8*>(
                    &Wb[((long long)(oc16g + mi) * NKS + ks) * 512 + lane * 8]);
#pragma unroll
            for (int nf = 0; nf < 2; ++nf) {
                int px = pxw + nf * 16 + l15;
                int swzr = ((px >> 2) & 7) * 8;
                bv[nf] = *reinterpret_cast<const bf16x8*>(&xs[px][koff ^ swzr]);
            }
#pragma unroll
            for (int mi = 0; mi < 2; ++mi)
#pragma unroll
                for (int nf = 0; nf < 2; ++nf)
                    acc[mi][nf] = __builtin_amdgcn_mfma_f32_16x16x32_bf16(
                        a[mi], bv[nf], acc[mi][nf], 0, 0, 0);
        }

#pragma unroll
        for (int mi = 0; mi < 2; ++mi)
#pragma unroll
            for (int nf = 0; nf < 2; ++nf) {
                int x = pxw + nf * 16 + l15;
#pragma unroll
                for (int r = 0; r < 4; ++r) {
                    int oc = ocw + mi * 16 + lk * 4 + r;
                    stF(&out[(long long)b * bs_out + (long long)oc * NPIX + nb + x],
                        acc[mi][nf][r]);
                }
            }
    }
}

// ---------------------------------------------------------------------------
// Grouped / depthwise 3x3 conv, pad 1 (unchanged).
// ---------------------------------------------------------------------------
template <int GIN, int GOUT, int ROWS>
__global__ __launch_bounds__(256) void dwconv3x3_kernel(
    const bf16* __restrict__ in, const float* __restrict__ Wm,
    const float* __restrict__ bias, bf16* __restrict__ out, int groups)
{
    __shared__ float xs[GIN][ROWS + 2][132];
    int tid = threadIdx.x;
    int g = blockIdx.y;
    int b = blockIdx.z;
    int y0 = blockIdx.x * ROWS;
    long long bsin = (long long)groups * GIN * NPIX;
    long long bsout = (long long)groups * GOUT * NPIX;
    const bf16* inb = in + (long long)b * bsin;

    constexpr int NLOAD = GIN * (ROWS + 2) * 32;
    for (int idx = tid; idx < NLOAD; idx += 256) {
        int seg = idx & 31;
        int r = (idx >> 5) % (ROWS + 2);
        int ic = idx / (32 * (ROWS + 2));
        int yy = y0 + r - 1;
        float f0 = 0.f, f1 = 0.f, f2 = 0.f, f3 = 0.f;
        if (yy >= 0 && yy < HH) {
            ushort4 u = *reinterpret_cast<const ushort4*>(
                &inb[(long long)(g * GIN + ic) * NPIX + yy * WW + seg * 4]);
            f0 = b2f(u.x); f1 = b2f(u.y); f2 = b2f(u.z); f3 = b2f(u.w);
        }
        float* dst = &xs[ic][r][seg * 4 + 1];
        dst[0] = f0; dst[1] = f1; dst[2] = f2; dst[3] = f3;
    }
    for (int idx = tid; idx < GIN * (ROWS + 2); idx += 256) {
        int r = idx % (ROWS + 2), ic = idx / (ROWS + 2);
        xs[ic][r][0] = 0.f;
        xs[ic][r][129] = 0.f;
    }
    __syncthreads();

    constexpr int NOUT2 = GOUT * ROWS * 64;
    for (int e = tid; e < NOUT2; e += 256) {
        int px2 = (e & 63) * 2;
        int comb = e >> 6;
        int ry = comb % ROWS;
        int oc = comb / ROWS;
        int ocg = g * GOUT + oc;
        const float* wp = Wm + (long long)ocg * GIN * 9;
        float acc0 = bias[ocg];
        float acc1 = acc0;
#pragma unroll
        for (int ic = 0; ic < GIN; ++ic)
#pragma unroll
            for (int ky = 0; ky < 3; ++ky)
#pragma unroll
                for (int kx = 0; kx < 3; ++kx) {
                    float wv = wp[ic * 9 + ky * 3 + kx];
                    acc0 = fmaf(wv, xs[ic][ry + ky][px2 + kx], acc0);
                    acc1 = fmaf(wv, xs[ic][ry + ky][px2 + 1 + kx], acc1);
                }
        ushort2 st;
        st.x = bfbits(acc0);
        st.y = bfbits(acc1);
        *reinterpret_cast<ushort2*>(
            &out[(long long)b * bsout + (long long)ocg * NPIX + (y0 + ry) * WW + px2]) = st;
    }
}

// ---------------------------------------------------------------------------
// NCHW fp32 -> NHWC bf16 transpose-convert (unchanged).
// ---------------------------------------------------------------------------
__global__ __launch_bounds__(256) void nchw2nhwc_kernel(
    const float* __restrict__ in, unsigned short* __restrict__ outp)
{
    __shared__ float xs[192][65];
    int tid = threadIdx.x;
    int y = blockIdx.x >> 1;
    int x0 = (blockIdx.x & 1) * 64;
    int b = blockIdx.z;

    for (int idx = tid; idx < 192 * 64; idx += 256) {
        int ic = idx >> 6, px = idx & 63;
        xs[ic][px] = in[(((long long)b * CDIM + ic) << 14) + y * WW + x0 + px];
    }
    __syncthreads();
    for (int idx = tid; idx < 64 * 24; idx += 256) {
        int px = idx / 24, grp = idx % 24;
        union { unsigned short u[8]; uint4 v; } pk;
#pragma unroll
        for (int j = 0; j < 8; ++j) pk.u[j] = bfbits(xs[grp * 8 + j][px]);
        *reinterpret_cast<uint4*>(
            &outp[(((long long)b * HH + y) * WW + x0 + px) * CDIM + grp * 8]) = pk.v;
    }
}

// ---------------------------------------------------------------------------
// Dense 3x3 conv 192->384 via MFMA implicit GEMM (unchanged from R7).
// ---------------------------------------------------------------------------
__global__ __launch_bounds__(256) void conv3x3_mfma_kernel(
    const unsigned short* __restrict__ Xbf,
    const unsigned short* __restrict__ Wc,
    const float* __restrict__ bias,
    bf16* __restrict__ out)
{
    __shared__ unsigned short xs[3][130][64];
    int tid = threadIdx.x;
    int lane = tid & 63;
    int wave = tid >> 6;
    int w_oc = wave >> 1;
    int w_px = wave & 1;
    int l15 = lane & 15;
    int lk = lane >> 4;

    int y = blockIdx.x;
    int b = blockIdx.z;
    int ocw = blockIdx.y * 64 + w_oc * 32;
    int oc16g = blockIdx.y * 4 + w_oc * 2;

    f32x4 acc[2][4];
#pragma unroll
    for (int mi = 0; mi < 2; ++mi)
#pragma unroll
        for (int r = 0; r < 4; ++r) {
            float bz = bias[ocw + mi * 16 + lk * 4 + r];
#pragma unroll
            for (int nf = 0; nf < 4; ++nf) acc[mi][nf][r] = bz;
        }

    for (int chunk = 0; chunk < 3; ++chunk) {
        int ic0 = chunk * 64;
        __syncthreads();
        for (int idx = tid; idx < 3 * 130 * 8; idx += 256) {
            int grp = idx & 7;
            int col = (idx >> 3) % 130;
            int ky = idx / (8 * 130);
            int yy = y + ky - 1;
            int xx = col - 1;
            uint4 val = make_uint4(0u, 0u, 0u, 0u);
            if (yy >= 0 && yy < HH && xx >= 0 && xx < WW)
                val = *reinterpret_cast<const uint4*>(
                    &Xbf[(((long long)b * HH + yy) * WW + xx) * CDIM + ic0 + grp * 8]);
            int slot = grp ^ (col & 7);
            *reinterpret_cast<uint4*>(&xs[ky][col][slot * 8]) = val;
        }
        __syncthreads();

#pragma unroll
        for (int tap = 0; tap < 9; ++tap) {
            int ky = tap / 3, kx = tap % 3;
#pragma unroll
            for (int ks = 0; ks < 2; ++ks) {
                int ksg = chunk * 2 + ks;
                bf16x8 a[2];
#pragma unroll
                for (int mi = 0; mi < 2; ++mi)
                    a[mi] = *reinterpret_cast<const bf16x8*>(
                        &Wc[((((long long)(oc16g + mi) * 9 + tap) * 6 + ksg) << 9) + lane * 8]);
                bf16x8 bv[4];
#pragma unroll
                for (int nf = 0; nf < 4; ++nf) {
                    int col = w_px * 64 + nf * 16 + l15 + kx;
                    int slot = (ks * 4 + lk) ^ (col & 7);
                    bv[nf] = *reinterpret_cast<const bf16x8*>(&xs[ky][col][slot * 8]);
                }
#pragma unroll
                for (int mi = 0; mi < 2; ++mi)
#pragma unroll
                    for (int nf = 0; nf < 4; ++nf)
                        acc[mi][nf] = __builtin_amdgcn_mfma_f32_16x16x32_bf16(
                            a[mi], bv[nf], acc[mi][nf], 0, 0, 0);
            }
        }
    }

#pragma unroll
    for (int mi = 0; mi < 2; ++mi)
#pragma unroll
        for (int nf = 0; nf < 4; ++nf) {
            int x = w_px * 64 + nf * 16 + l15;
#pragma unroll
            for (int r = 0; r < 4; ++r) {
                int oc = ocw + mi * 16 + lk * 4 + r;
                stF(&out[(((long long)b * 384 + oc) << 14) + y * WW + x], acc[mi][nf][r]);
            }
        }
}

// ---------------------------------------------------------------------------
// Gram + sumsq via MFMA. Grid (32 bh, 16 seg); block 256 = 4 waves.
// Per wave: 8 K-steps of 32 px. G = Q K^T via 2x2 tiles of 16x16x32;
// Q Q^T / K K^T / V V^T self-products give the three sumsq vectors from
// their diagonals (free in the MFMA pipe). Channels >=24 within the padded
// 32-row tiles are loaded (in-bounds workspace) but never stored.
// Cross-wave Gram reduce in LDS, one global atomicAdd per element.
// ---------------------------------------------------------------------------
__global__ __launch_bounds__(256) void gram_mfma_kernel(
    const unsigned short* __restrict__ q, long long bsq,
    const unsigned short* __restrict__ k, long long bsk,
    const unsigned short* __restrict__ v, long long bsv,
    float* __restrict__ ssq, float* __restrict__ gram)
{
    __shared__ float gl[4][24][25];
    int bh = blockIdx.x;
    int b = bh >> 3, h = bh & 7;
    int n0 = blockIdx.y * 1024;
    int tid = threadIdx.x;
    int lane = tid & 63;
    int wave = tid >> 6;
    int l15 = lane & 15;
    int lk = lane >> 4;

    const unsigned short* qb = q + (long long)b * bsq + (long long)(h * CP) * NPIX;
    const unsigned short* kb = k + (long long)b * bsk + (long long)(h * CP) * NPIX;
    const unsigned short* vb = v + (long long)b * bsv + (long long)(h * CP) * NPIX;

    f32x4 acc[2][2], aqq[2], akk[2], avv[2];
#pragma unroll
    for (int mt = 0; mt < 2; ++mt) {
#pragma unroll
        for (int nt = 0; nt < 2; ++nt) acc[mt][nt] = {0.f, 0.f, 0.f, 0.f};
        aqq[mt] = {0.f, 0.f, 0.f, 0.f};
        akk[mt] = {0.f, 0.f, 0.f, 0.f};
        avv[mt] = {0.f, 0.f, 0.f, 0.f};
    }

#pragma unroll 2
    for (int st = 0; st < 8; ++st) {
        int px = n0 + wave * 256 + st * 32 + lk * 8;
        bf16x8 aq[2], bk[2], av[2];
#pragma unroll
        for (int mt = 0; mt < 2; ++mt) {
            long long off = (long long)(mt * 16 + l15) * NPIX + px;
            aq[mt] = *reinterpret_cast<const bf16x8*>(&qb[off]);
            bk[mt] = *reinterpret_cast<const bf16x8*>(&kb[off]);
            av[mt] = *reinterpret_cast<const bf16x8*>(&vb[off]);
        }
#pragma unroll
        for (int mt = 0; mt < 2; ++mt)
#pragma unroll
            for (int nt = 0; nt < 2; ++nt)
                acc[mt][nt] = __builtin_amdgcn_mfma_f32_16x16x32_bf16(
                    aq[mt], bk[nt], acc[mt][nt], 0, 0, 0);
#pragma unroll
        for (int mt = 0; mt < 2; ++mt) {
            aqq[mt] = __builtin_amdgcn_mfma_f32_16x16x32_bf16(aq[mt], aq[mt], aqq[mt], 0, 0, 0);
            akk[mt] = __builtin_amdgcn_mfma_f32_16x16x32_bf16(bk[mt], bk[mt], akk[mt], 0, 0, 0);
            avv[mt] = __builtin_amdgcn_mfma_f32_16x16x32_bf16(av[mt], av[mt], avv[mt], 0, 0, 0);
        }
    }

    // sumsq: diagonal lanes (row == col within tile)
    if (lk == (l15 >> 2)) {
        int r = l15 & 3;
#pragma unroll
        for (int mt = 0; mt < 2; ++mt) {
            int ch = mt * 16 + l15;
            if (ch < CP) {
                int o = b * CDIM + h * CP + ch;
                atomicAdd(&ssq[o], aqq[mt][r]);
                atomicAdd(&ssq[NB * CDIM + o], akk[mt][r]);
                atomicAdd(&ssq[2 * NB * CDIM + o], avv[mt][r]);
            }
        }
    }

    // Gram: per-wave LDS slots, then summed + one global atomic per element
#pragma unroll
    for (int mt = 0; mt < 2; ++mt)
#pragma unroll
        for (int nt = 0; nt < 2; ++nt)
#pragma unroll
            for (int r = 0; r < 4; ++r) {
                int cq = mt * 16 + lk * 4 + r;
                int ck = nt * 16 + l15;
                if (cq < CP && ck < CP) gl[wave][cq][ck] = acc[mt][nt][r];
            }
    __syncthreads();
    for (int e = tid; e < CP * CP; e += 256) {
        int cq = e / CP, ck = e % CP;
        float s = gl[0][cq][ck] + gl[1][cq][ck] + gl[2][cq][ck] + gl[3][cq][ck];
        atomicAdd(&gram[(long long)bh * (CP * CP) + e], s);
    }
}

// ---------------------------------------------------------------------------
// Softmax + fold norms + proj -> per-batch M, packed layout (unchanged).
// ---------------------------------------------------------------------------
__global__ __launch_bounds__(256) void build_M_kernel(
    const float* __restrict__ ssq, const float* __restrict__ gram,
    const float* __restrict__ temp, const float* __restrict__ proj_w,
    unsigned short* __restrict__ Mout)
{
    __shared__ float A[HEADS][CP][CP];
    __shared__ float nq[CDIM], nk[CDIM], nv[CDIM];
    int b = blockIdx.x;
    int tid = threadIdx.x;
    if (tid < CDIM) {
        nq[tid] = fmaxf(sqrtf(ssq[0 * (NB * CDIM) + b * CDIM + tid]), 1e-12f);
        nk[tid] = fmaxf(sqrtf(ssq[1 * (NB * CDIM) + b * CDIM + tid]), 1e-12f);
        nv[tid] = fmaxf(sqrtf(ssq[2 * (NB * CDIM) + b * CDIM + tid]), 1e-12f);
    }
    __syncthreads();
    if (tid < CDIM) {
        int h = tid / CP, cq = tid % CP;
        float t = temp[h];
        float row[CP];
        float m = -1e30f;
#pragma unroll
        for (int ck = 0; ck < CP; ++ck) {
            float g = gram[(long long)b * (HEADS * 576) + h * 576 + cq * CP + ck];
            g = g / (nq[h * CP + cq] * nk[h * CP + ck]) * t;
            row[ck] = g;
            m = fmaxf(m, g);
        }
        float s = 0.f;
#pragma unroll
        for (int ck = 0; ck < CP; ++ck) { row[ck] = __expf(row[ck] - m); s += row[ck]; }
        float inv = 1.f / s;
#pragma unroll
        for (int ck = 0; ck < CP; ++ck)
            A[h][cq][ck] = row[ck] * inv / nv[h * CP + ck];
    }
    __syncthreads();
    for (int e = tid; e < CDIM * CDIM; e += 256) {
        int oc = e / CDIM, d = e % CDIM;
        int h2 = d / CP, ck = d % CP;
        float acc = 0.f;
#pragma unroll
        for (int cq = 0; cq < CP; ++cq)
            acc = fmaf(proj_w[(long long)oc * CDIM + h2 * CP + cq], A[h2][cq][ck], acc);
        int oc16 = oc >> 4, l15 = oc & 15;
        int ksg = d >> 5, lk = (d >> 3) & 3, j = d & 7;
        int lanep = lk * 16 + l15;
        Mout[(long long)b * (CDIM * CDIM) + (((oc16 * 6 + ksg) << 6) + lanep) * 8 + j] =
            bfbits(acc);
    }
}

__global__ void zero_kernel(float* __restrict__ p, int n)
{
    for (int i = blockIdx.x * 256 + threadIdx.x; i < n; i += gridDim.x * 256) p[i] = 0.f;
}

// ---------------------------------------------------------------------------
// Workspace layout identical to R5-R7 (< 202 MB).
// ---------------------------------------------------------------------------
extern "C" void kernel_launch(void* const* d_in, const int* in_sizes, int n_in,
                              void* d_out, int out_size, void* d_ws, size_t ws_size,
                              hipStream_t stream)
{
    const float* x      = (const float*)d_in[0];
    const float* x_mask = (const float*)d_in[1];
    const float* temp   = (const float*)d_in[2];
    const float* q_w    = (const float*)d_in[3];
    const float* q_b    = (const float*)d_in[4];
    const float* qdw_w  = (const float*)d_in[5];
    const float* qdw_b  = (const float*)d_in[6];
    const float* kv_w   = (const float*)d_in[7];
    const float* kv_b   = (const float*)d_in[8];
    const float* kvdw_w = (const float*)d_in[9];
    const float* kvdw_b = (const float*)d_in[10];
    const float* newk_w = (const float*)d_in[11];
    const float* newk_b = (const float*)d_in[12];
    const float* newv_w = (const float*)d_in[13];
    const float* newv_b = (const float*)d_in[14];
    const float* proj_w = (const float*)d_in[15];
    const float* proj_b = (const float*)d_in[16];

    char* wsb = (char*)d_ws;
    bf16* A  = (bf16*)wsb;
    bf16* Bq = (bf16*)(wsb + 75497472);
    bf16* C  = (bf16*)(wsb + 150994944);
    unsigned short* qwb   = (unsigned short*)Bq;                    // 110,592
    unsigned short* nkb   = (unsigned short*)A + 25165824;          // 73,728
    unsigned short* nvb   = (unsigned short*)A + 25239552;          // 73,728
    unsigned short* Mbf   = (unsigned short*)A + 25313280;          // 147,456
    unsigned short* Wpack = (unsigned short*)C;                     // 663,552
    unsigned short* Xbf   = (unsigned short*)C + 663552;            // 12,582,912
    float* stats = (float*)(wsb + 201326592);
    float* ssq  = stats;                                            // 2304
    float* gram = ssq + 2304;                                       // 18432

    const long long N = NPIX;
    float* out = (float*)d_out;

    // stats zero + weight packs needed before S1
    zero_kernel<<<16, 256, 0, stream>>>(ssq, 2304 + 18432);
    pack_w1x1_kernel<<<432, 256, 0, stream>>>(q_w, qwb, 576, 192);
    pack_wconv_kernel<<<(384 * 9 * 192 + 255) / 256, 256, 0, stream>>>(kv_w, Wpack);

    // S1: qkv1 = conv1x1(x, q_w) : 192 -> 576 (fp32 in, bf16 out) -> A
    gemm1x1_allK_kernel<float, bf16, 192, 9, 200><<<dim3(256, 1, 4), 256, 0, stream>>>(
        x, 192 * N, x, 0, 192, qwb, 0, q_b, A, 576 * N);

    // S2: qkv = grouped 3x3 (groups=192, 3in/3out) -> B
    dwconv3x3_kernel<3, 3, 8><<<dim3(16, 192, 4), 256, 0, stream>>>(
        A, qdw_w, qdw_b, Bq, 192);

    // packs into A-tail (A dead after S2) + NHWC convert into C
    pack_w1x1_kernel<<<288, 256, 0, stream>>>(newk_w, nkb, 192, 384);
    pack_w1x1_kernel<<<288, 256, 0, stream>>>(newv_w, nvb, 192, 384);
    nchw2nhwc_kernel<<<dim3(256, 1, 4), 256, 0, stream>>>(x_mask, Xbf);

    // S3: kv1 = dense conv3x3(x_mask) 192->384 via MFMA -> A[0:25.17M)
    conv3x3_mfma_kernel<<<dim3(128, 6, 4), 256, 0, stream>>>(Xbf, Wpack, kv_b, A);

    // S4: kv2 = depthwise 3x3 (384 groups) -> C (overwrites Wpack/Xbf, done)
    dwconv3x3_kernel<1, 1, 16><<<dim3(8, 384, 4), 256, 0, stream>>>(
        A, kvdw_w, kvdw_b, C, 384);

    // S5: k_new / v_new = conv1x1 of concat (IC=384), MFMA -> A[0:25.17M)
    bf16* k_new = A;
    bf16* v_new = A + 12582912;
    gemm1x1_allK_kernel<bf16, bf16, 384, 3, 392><<<dim3(256, 1, 4), 256, 0, stream>>>(
        Bq + 192 * N, 576 * N, C, 384 * N, 192, nkb, 0, newk_b, k_new, 192 * N);
    gemm1x1_allK_kernel<bf16, bf16, 384, 3, 392><<<dim3(256, 1, 4), 256, 0, stream>>>(
        Bq + 384 * N, 576 * N, C + 192 * N, 384 * N, 192, nvb, 0, newv_b, v_new, 192 * N);

    // S6: sumsq(q,k,v) + Gram(q,k) via MFMA
    gram_mfma_kernel<<<dim3(32, 16), 256, 0, stream>>>(
        (const unsigned short*)Bq, 576 * N,
        (const unsigned short*)k_new, 192 * N,
        (const unsigned short*)v_new, 192 * N, ssq, gram);

    // S7: softmax + fold v-norm + proj -> per-batch M (bf16, packed layout)
    build_M_kernel<<<4, 256, 0, stream>>>(ssq, gram, temp, proj_w, Mbf);

    // S8: out = M_b @ v_new + proj_b (bf16 in, fp32 out)
    gemm1x1_allK_kernel<bf16, float, 192, 3, 200><<<dim3(256, 1, 4), 256, 0, stream>>>(
        v_new, 192 * N, v_new, 0, 192, Mbf, (long long)CDIM * CDIM, proj_b, out, 192 * N);
}

// Round 9
// 447.853 us; speedup vs baseline: 1.9692x; 1.0917x over previous
//
#include <hip/hip_runtime.h>
#include <hip/hip_bf16.h>

// Problem constants
#define NB 4
#define CDIM 192
#define HEADS 8
#define CP 24
#define HH 128
#define WW 128
#define NPIX 16384  // 128*128

typedef __hip_bfloat16 bf16;
typedef __bf16 bf16x8 __attribute__((ext_vector_type(8)));
typedef float f32x4 __attribute__((ext_vector_type(4)));

__device__ __forceinline__ float toF(float v) { return v; }
__device__ __forceinline__ float toF(bf16 v) { return __bfloat162float(v); }
__device__ __forceinline__ void stF(float* p, float v) { *p = v; }
__device__ __forceinline__ void stF(bf16* p, float v) { *p = __float2bfloat16(v); }
__device__ __forceinline__ unsigned short bfbits(float v) {
    bf16 h = __float2bfloat16(v);
    return *reinterpret_cast<unsigned short*>(&h);
}
__device__ __forceinline__ float b2f(unsigned short u) {
    union { unsigned int i; float f; } c;
    c.i = ((unsigned int)u) << 16;
    return c.f;
}

// ===========================================================================
// Weight packing: lane-ordered coalesced MFMA A-operand layout (unchanged).
// ===========================================================================
__global__ __launch_bounds__(256) void pack_w1x1_kernel(
    const float* __restrict__ w, unsigned short* __restrict__ wp, int OC, int IC)
{
    int e = blockIdx.x * 256 + threadIdx.x;
    if (e >= OC * IC) return;
    int j = e & 7, lane = (e >> 3) & 63, rest = e >> 9;
    int nks = IC >> 5;
    int ksg = rest % nks, oc16 = rest / nks;
    int oc = oc16 * 16 + (lane & 15);
    int ic = ksg * 32 + (lane >> 4) * 8 + j;
    wp[e] = bfbits(w[(long long)oc * IC + ic]);
}

__global__ __launch_bounds__(256) void pack_wconv_kernel(
    const float* __restrict__ w, unsigned short* __restrict__ wp)
{
    int e = blockIdx.x * 256 + threadIdx.x;
    if (e >= 384 * 9 * 192) return;
    int j = e & 7, lane = (e >> 3) & 63, rest = e >> 9;
    int ksg = rest % 6; rest /= 6;
    int tap = rest % 9;
    int oc16 = rest / 9;
    int oc = oc16 * 16 + (lane & 15);
    int ic = ksg * 32 + (lane >> 4) * 8 + j;
    wp[e] = bfbits(w[((long long)oc * 192 + ic) * 9 + tap]);
}

// ---------------------------------------------------------------------------
// 1x1-conv GEMM via bf16 MFMA, stage-K-once, coalesced packed weights.
// (unchanged from R8)
// ---------------------------------------------------------------------------
template <typename TI, typename TO, int IC, int OCT, int ICPAD>
__global__ __launch_bounds__(256) void gemm1x1_allK_kernel(
    const TI* __restrict__ in0, long long bs0,
    const TI* __restrict__ in1, long long bs1, int ic_split,
    const unsigned short* __restrict__ Wbf, long long w_bs,
    const float* __restrict__ bias,
    TO* __restrict__ out, long long bs_out)
{
    __shared__ unsigned short xs[64][ICPAD];
    int tid = threadIdx.x;
    int lane = tid & 63;
    int wave = tid >> 6;
    int w_oc = wave >> 1;
    int w_px = wave & 1;
    int l15 = lane & 15;
    int lk  = lane >> 4;
    constexpr int NKS = IC / 32;

    int nb = blockIdx.x * 64;
    int b  = blockIdx.z;
    const unsigned short* Wb = Wbf + (long long)b * w_bs;

    for (int u = tid; u < (IC / 4) * 16; u += 256) {
        int px = (u & 15) * 4;
        int ic = (u >> 4) * 4;
        unsigned short rb[4][4];
#pragma unroll
        for (int j = 0; j < 4; ++j) {
            int ch = ic + j;
            const TI* p;
            if (ch < ic_split)
                p = in0 + (long long)b * bs0 + (long long)ch * NPIX + nb + px;
            else
                p = in1 + (long long)b * bs1 + (long long)(ch - ic_split) * NPIX + nb + px;
            if constexpr (sizeof(TI) == 4) {
                float4 v = *reinterpret_cast<const float4*>(p);
                rb[j][0] = bfbits(v.x); rb[j][1] = bfbits(v.y);
                rb[j][2] = bfbits(v.z); rb[j][3] = bfbits(v.w);
            } else {
                ushort4 v = *reinterpret_cast<const ushort4*>(p);
                rb[j][0] = v.x; rb[j][1] = v.y; rb[j][2] = v.z; rb[j][3] = v.w;
            }
        }
        int swz = ((px >> 2) & 7) * 8;
#pragma unroll
        for (int i = 0; i < 4; ++i) {
            union { unsigned short s[4]; uint2 v; } pk;
            pk.s[0] = rb[0][i]; pk.s[1] = rb[1][i];
            pk.s[2] = rb[2][i]; pk.s[3] = rb[3][i];
            *reinterpret_cast<uint2*>(&xs[px + i][ic ^ swz]) = pk.v;
        }
    }
    __syncthreads();

    int pxw = w_px * 32;
#pragma unroll 1
    for (int ot = 0; ot < OCT; ++ot) {
        int ocw = ot * 64 + w_oc * 32;
        int oc16g = ot * 4 + w_oc * 2;
        f32x4 acc[2][2];
#pragma unroll
        for (int mi = 0; mi < 2; ++mi)
#pragma unroll
            for (int r = 0; r < 4; ++r) {
                float bz = bias[ocw + mi * 16 + lk * 4 + r];
#pragma unroll
                for (int nf = 0; nf < 2; ++nf) acc[mi][nf][r] = bz;
            }

#pragma unroll
        for (int ks = 0; ks < NKS; ++ks) {
            int koff = ks * 32 + lk * 8;
            bf16x8 a[2], bv[2];
#pragma unroll
            for (int mi = 0; mi < 2; ++mi)
                a[mi] = *reinterpret_cast<const bf16x8*>(
                    &Wb[((long long)(oc16g + mi) * NKS + ks) * 512 + lane * 8]);
#pragma unroll
            for (int nf = 0; nf < 2; ++nf) {
                int px = pxw + nf * 16 + l15;
                int swzr = ((px >> 2) & 7) * 8;
                bv[nf] = *reinterpret_cast<const bf16x8*>(&xs[px][koff ^ swzr]);
            }
#pragma unroll
            for (int mi = 0; mi < 2; ++mi)
#pragma unroll
                for (int nf = 0; nf < 2; ++nf)
                    acc[mi][nf] = __builtin_amdgcn_mfma_f32_16x16x32_bf16(
                        a[mi], bv[nf], acc[mi][nf], 0, 0, 0);
        }

#pragma unroll
        for (int mi = 0; mi < 2; ++mi)
#pragma unroll
            for (int nf = 0; nf < 2; ++nf) {
                int x = pxw + nf * 16 + l15;
#pragma unroll
                for (int r = 0; r < 4; ++r) {
                    int oc = ocw + mi * 16 + lk * 4 + r;
                    stF(&out[(long long)b * bs_out + (long long)oc * NPIX + nb + x],
                        acc[mi][nf][r]);
                }
            }
    }
}

// ---------------------------------------------------------------------------
// Grouped / depthwise 3x3 conv, pad 1 (unchanged).
// ---------------------------------------------------------------------------
template <int GIN, int GOUT, int ROWS>
__global__ __launch_bounds__(256) void dwconv3x3_kernel(
    const bf16* __restrict__ in, const float* __restrict__ Wm,
    const float* __restrict__ bias, bf16* __restrict__ out, int groups)
{
    __shared__ float xs[GIN][ROWS + 2][132];
    int tid = threadIdx.x;
    int g = blockIdx.y;
    int b = blockIdx.z;
    int y0 = blockIdx.x * ROWS;
    long long bsin = (long long)groups * GIN * NPIX;
    long long bsout = (long long)groups * GOUT * NPIX;
    const bf16* inb = in + (long long)b * bsin;

    constexpr int NLOAD = GIN * (ROWS + 2) * 32;
    for (int idx = tid; idx < NLOAD; idx += 256) {
        int seg = idx & 31;
        int r = (idx >> 5) % (ROWS + 2);
        int ic = idx / (32 * (ROWS + 2));
        int yy = y0 + r - 1;
        float f0 = 0.f, f1 = 0.f, f2 = 0.f, f3 = 0.f;
        if (yy >= 0 && yy < HH) {
            ushort4 u = *reinterpret_cast<const ushort4*>(
                &inb[(long long)(g * GIN + ic) * NPIX + yy * WW + seg * 4]);
            f0 = b2f(u.x); f1 = b2f(u.y); f2 = b2f(u.z); f3 = b2f(u.w);
        }
        float* dst = &xs[ic][r][seg * 4 + 1];
        dst[0] = f0; dst[1] = f1; dst[2] = f2; dst[3] = f3;
    }
    for (int idx = tid; idx < GIN * (ROWS + 2); idx += 256) {
        int r = idx % (ROWS + 2), ic = idx / (ROWS + 2);
        xs[ic][r][0] = 0.f;
        xs[ic][r][129] = 0.f;
    }
    __syncthreads();

    constexpr int NOUT2 = GOUT * ROWS * 64;
    for (int e = tid; e < NOUT2; e += 256) {
        int px2 = (e & 63) * 2;
        int comb = e >> 6;
        int ry = comb % ROWS;
        int oc = comb / ROWS;
        int ocg = g * GOUT + oc;
        const float* wp = Wm + (long long)ocg * GIN * 9;
        float acc0 = bias[ocg];
        float acc1 = acc0;
#pragma unroll
        for (int ic = 0; ic < GIN; ++ic)
#pragma unroll
            for (int ky = 0; ky < 3; ++ky)
#pragma unroll
                for (int kx = 0; kx < 3; ++kx) {
                    float wv = wp[ic * 9 + ky * 3 + kx];
                    acc0 = fmaf(wv, xs[ic][ry + ky][px2 + kx], acc0);
                    acc1 = fmaf(wv, xs[ic][ry + ky][px2 + 1 + kx], acc1);
                }
        ushort2 st;
        st.x = bfbits(acc0);
        st.y = bfbits(acc1);
        *reinterpret_cast<ushort2*>(
            &out[(long long)b * bsout + (long long)ocg * NPIX + (y0 + ry) * WW + px2]) = st;
    }
}

// ---------------------------------------------------------------------------
// NCHW fp32 -> NHWC bf16 transpose-convert (unchanged).
// ---------------------------------------------------------------------------
__global__ __launch_bounds__(256) void nchw2nhwc_kernel(
    const float* __restrict__ in, unsigned short* __restrict__ outp)
{
    __shared__ float xs[192][65];
    int tid = threadIdx.x;
    int y = blockIdx.x >> 1;
    int x0 = (blockIdx.x & 1) * 64;
    int b = blockIdx.z;

    for (int idx = tid; idx < 192 * 64; idx += 256) {
        int ic = idx >> 6, px = idx & 63;
        xs[ic][px] = in[(((long long)b * CDIM + ic) << 14) + y * WW + x0 + px];
    }
    __syncthreads();
    for (int idx = tid; idx < 64 * 24; idx += 256) {
        int px = idx / 24, grp = idx % 24;
        union { unsigned short u[8]; uint4 v; } pk;
#pragma unroll
        for (int j = 0; j < 8; ++j) pk.u[j] = bfbits(xs[grp * 8 + j][px]);
        *reinterpret_cast<uint4*>(
            &outp[(((long long)b * HH + y) * WW + x0 + px) * CDIM + grp * 8]) = pk.v;
    }
}

// ---------------------------------------------------------------------------
// Dense 3x3 conv 192->384 via MFMA implicit GEMM, 2-output-row tiles.
// Stages 4 rows (y0-1..y0+2) x 66 cols x 64 ic (33 KB -> 4 blocks/CU);
// each interior staged row serves BOTH output rows (ky and ky-1), cutting
// ds_reads/FLOP by 33% and staging/FLOP by 31% vs the 1-row version.
// A-frags for all 3 ky hoisted to registers per (kx,ks) (static indexing).
// Conflict-free XOR swizzle slot=grp^(col&7) as before. Block 256 = 4 waves
// (2 oc x 2 px); wave tile 32 oc x 32 px x 2 rows.
// Grid: (64 ypair * 2 xhalf, 6 ocb, 4 b).
// ---------------------------------------------------------------------------
__global__ __launch_bounds__(256) void conv3x3_mfma_kernel(
    const unsigned short* __restrict__ Xbf,
    const unsigned short* __restrict__ Wc,
    const float* __restrict__ bias,
    bf16* __restrict__ out)
{
    __shared__ unsigned short xs[4][66][64];
    int tid = threadIdx.x;
    int lane = tid & 63;
    int wave = tid >> 6;
    int w_oc = wave >> 1;
    int w_px = wave & 1;
    int l15 = lane & 15;
    int lk = lane >> 4;

    int ypair = blockIdx.x >> 1;
    int xstart = (blockIdx.x & 1) * 64;
    int y0 = ypair * 2;
    int b = blockIdx.z;
    int ocw = blockIdx.y * 64 + w_oc * 32;
    int oc16g = blockIdx.y * 4 + w_oc * 2;

    f32x4 acc[2][2][2];  // [yo][mi][nf]
#pragma unroll
    for (int mi = 0; mi < 2; ++mi)
#pragma unroll
        for (int r = 0; r < 4; ++r) {
            float bz = bias[ocw + mi * 16 + lk * 4 + r];
#pragma unroll
            for (int yo = 0; yo < 2; ++yo)
#pragma unroll
                for (int nf = 0; nf < 2; ++nf) acc[yo][mi][nf][r] = bz;
        }

    for (int chunk = 0; chunk < 3; ++chunk) {
        int ic0 = chunk * 64;
        __syncthreads();
        // stage [4 rows][66 cols][64 ic] bf16, swizzled 16B slots
        for (int idx = tid; idx < 4 * 66 * 8; idx += 256) {
            int grp = idx & 7;
            int col = (idx >> 3) % 66;
            int r = idx / (8 * 66);
            int yy = y0 + r - 1;
            int xx = xstart + col - 1;
            uint4 val = make_uint4(0u, 0u, 0u, 0u);
            if (yy >= 0 && yy < HH && xx >= 0 && xx < WW)
                val = *reinterpret_cast<const uint4*>(
                    &Xbf[(((long long)b * HH + yy) * WW + xx) * CDIM + ic0 + grp * 8]);
            int slot = grp ^ (col & 7);
            *reinterpret_cast<uint4*>(&xs[r][col][slot * 8]) = val;
        }
        __syncthreads();
        __builtin_amdgcn_s_setprio(1);

#pragma unroll
        for (int kx = 0; kx < 3; ++kx) {
#pragma unroll
            for (int ks = 0; ks < 2; ++ks) {
                int ksg = chunk * 2 + ks;
                // hoist A-frags for all 3 ky (static indices -> registers)
                bf16x8 aw[3][2];
#pragma unroll
                for (int ky = 0; ky < 3; ++ky)
#pragma unroll
                    for (int mi = 0; mi < 2; ++mi)
                        aw[ky][mi] = *reinterpret_cast<const bf16x8*>(
                            &Wc[((((long long)(oc16g + mi) * 9 + ky * 3 + kx) * 6 + ksg) << 9)
                                + lane * 8]);
#pragma unroll
                for (int r = 0; r < 4; ++r) {
                    bf16x8 bv[2];
#pragma unroll
                    for (int nf = 0; nf < 2; ++nf) {
                        int col = w_px * 32 + nf * 16 + l15 + kx;
                        int slot = (ks * 4 + lk) ^ (col & 7);
                        bv[nf] = *reinterpret_cast<const bf16x8*>(&xs[r][col][slot * 8]);
                    }
#pragma unroll
                    for (int yo = 0; yo < 2; ++yo) {
                        int ky = r - yo;
                        if (ky >= 0 && ky <= 2) {
#pragma unroll
                            for (int mi = 0; mi < 2; ++mi)
#pragma unroll
                                for (int nf = 0; nf < 2; ++nf)
                                    acc[yo][mi][nf] = __builtin_amdgcn_mfma_f32_16x16x32_bf16(
                                        aw[ky][mi], bv[nf], acc[yo][mi][nf], 0, 0, 0);
                        }
                    }
                }
            }
        }
        __builtin_amdgcn_s_setprio(0);
    }

#pragma unroll
    for (int yo = 0; yo < 2; ++yo)
#pragma unroll
        for (int mi = 0; mi < 2; ++mi)
#pragma unroll
            for (int nf = 0; nf < 2; ++nf) {
                int x = xstart + w_px * 32 + nf * 16 + l15;
#pragma unroll
                for (int r = 0; r < 4; ++r) {
                    int oc = ocw + mi * 16 + lk * 4 + r;
                    stF(&out[(((long long)b * 384 + oc) << 14) + (y0 + yo) * WW + x],
                        acc[yo][mi][nf][r]);
                }
            }
}

// ---------------------------------------------------------------------------
// Gram + sumsq via MFMA (unchanged from R8).
// ---------------------------------------------------------------------------
__global__ __launch_bounds__(256) void gram_mfma_kernel(
    const unsigned short* __restrict__ q, long long bsq,
    const unsigned short* __restrict__ k, long long bsk,
    const unsigned short* __restrict__ v, long long bsv,
    float* __restrict__ ssq, float* __restrict__ gram)
{
    __shared__ float gl[4][24][25];
    int bh = blockIdx.x;
    int b = bh >> 3, h = bh & 7;
    int n0 = blockIdx.y * 1024;
    int tid = threadIdx.x;
    int lane = tid & 63;
    int wave = tid >> 6;
    int l15 = lane & 15;
    int lk = lane >> 4;

    const unsigned short* qb = q + (long long)b * bsq + (long long)(h * CP) * NPIX;
    const unsigned short* kb = k + (long long)b * bsk + (long long)(h * CP) * NPIX;
    const unsigned short* vb = v + (long long)b * bsv + (long long)(h * CP) * NPIX;

    f32x4 acc[2][2], aqq[2], akk[2], avv[2];
#pragma unroll
    for (int mt = 0; mt < 2; ++mt) {
#pragma unroll
        for (int nt = 0; nt < 2; ++nt) acc[mt][nt] = {0.f, 0.f, 0.f, 0.f};
        aqq[mt] = {0.f, 0.f, 0.f, 0.f};
        akk[mt] = {0.f, 0.f, 0.f, 0.f};
        avv[mt] = {0.f, 0.f, 0.f, 0.f};
    }

#pragma unroll 2
    for (int st = 0; st < 8; ++st) {
        int px = n0 + wave * 256 + st * 32 + lk * 8;
        bf16x8 aq[2], bk[2], av[2];
#pragma unroll
        for (int mt = 0; mt < 2; ++mt) {
            long long off = (long long)(mt * 16 + l15) * NPIX + px;
            aq[mt] = *reinterpret_cast<const bf16x8*>(&qb[off]);
            bk[mt] = *reinterpret_cast<const bf16x8*>(&kb[off]);
            av[mt] = *reinterpret_cast<const bf16x8*>(&vb[off]);
        }
#pragma unroll
        for (int mt = 0; mt < 2; ++mt)
#pragma unroll
            for (int nt = 0; nt < 2; ++nt)
                acc[mt][nt] = __builtin_amdgcn_mfma_f32_16x16x32_bf16(
                    aq[mt], bk[nt], acc[mt][nt], 0, 0, 0);
#pragma unroll
        for (int mt = 0; mt < 2; ++mt) {
            aqq[mt] = __builtin_amdgcn_mfma_f32_16x16x32_bf16(aq[mt], aq[mt], aqq[mt], 0, 0, 0);
            akk[mt] = __builtin_amdgcn_mfma_f32_16x16x32_bf16(bk[mt], bk[mt], akk[mt], 0, 0, 0);
            avv[mt] = __builtin_amdgcn_mfma_f32_16x16x32_bf16(av[mt], av[mt], avv[mt], 0, 0, 0);
        }
    }

    if (lk == (l15 >> 2)) {
        int r = l15 & 3;
#pragma unroll
        for (int mt = 0; mt < 2; ++mt) {
            int ch = mt * 16 + l15;
            if (ch < CP) {
                int o = b * CDIM + h * CP + ch;
                atomicAdd(&ssq[o], aqq[mt][r]);
                atomicAdd(&ssq[NB * CDIM + o], akk[mt][r]);
                atomicAdd(&ssq[2 * NB * CDIM + o], avv[mt][r]);
            }
        }
    }

#pragma unroll
    for (int mt = 0; mt < 2; ++mt)
#pragma unroll
        for (int nt = 0; nt < 2; ++nt)
#pragma unroll
            for (int r = 0; r < 4; ++r) {
                int cq = mt * 16 + lk * 4 + r;
                int ck = nt * 16 + l15;
                if (cq < CP && ck < CP) gl[wave][cq][ck] = acc[mt][nt][r];
            }
    __syncthreads();
    for (int e = tid; e < CP * CP; e += 256) {
        int cq = e / CP, ck = e % CP;
        float s = gl[0][cq][ck] + gl[1][cq][ck] + gl[2][cq][ck] + gl[3][cq][ck];
        atomicAdd(&gram[(long long)bh * (CP * CP) + e], s);
    }
}

// ---------------------------------------------------------------------------
// Softmax + fold norms + proj -> per-batch M, packed layout (unchanged).
// ---------------------------------------------------------------------------
__global__ __launch_bounds__(256) void build_M_kernel(
    const float* __restrict__ ssq, const float* __restrict__ gram,
    const float* __restrict__ temp, const float* __restrict__ proj_w,
    unsigned short* __restrict__ Mout)
{
    __shared__ float A[HEADS][CP][CP];
    __shared__ float nq[CDIM], nk[CDIM], nv[CDIM];
    int b = blockIdx.x;
    int tid = threadIdx.x;
    if (tid < CDIM) {
        nq[tid] = fmaxf(sqrtf(ssq[0 * (NB * CDIM) + b * CDIM + tid]), 1e-12f);
        nk[tid] = fmaxf(sqrtf(ssq[1 * (NB * CDIM) + b * CDIM + tid]), 1e-12f);
        nv[tid] = fmaxf(sqrtf(ssq[2 * (NB * CDIM) + b * CDIM + tid]), 1e-12f);
    }
    __syncthreads();
    if (tid < CDIM) {
        int h = tid / CP, cq = tid % CP;
        float t = temp[h];
        float row[CP];
        float m = -1e30f;
#pragma unroll
        for (int ck = 0; ck < CP; ++ck) {
            float g = gram[(long long)b * (HEADS * 576) + h * 576 + cq * CP + ck];
            g = g / (nq[h * CP + cq] * nk[h * CP + ck]) * t;
            row[ck] = g;
            m = fmaxf(m, g);
        }
        float s = 0.f;
#pragma unroll
        for (int ck = 0; ck < CP; ++ck) { row[ck] = __expf(row[ck] - m); s += row[ck]; }
        float inv = 1.f / s;
#pragma unroll
        for (int ck = 0; ck < CP; ++ck)
            A[h][cq][ck] = row[ck] * inv / nv[h * CP + ck];
    }
    __syncthreads();
    for (int e = tid; e < CDIM * CDIM; e += 256) {
        int oc = e / CDIM, d = e % CDIM;
        int h2 = d / CP, ck = d % CP;
        float acc = 0.f;
#pragma unroll
        for (int cq = 0; cq < CP; ++cq)
            acc = fmaf(proj_w[(long long)oc * CDIM + h2 * CP + cq], A[h2][cq][ck], acc);
        int oc16 = oc >> 4, l15 = oc & 15;
        int ksg = d >> 5, lk = (d >> 3) & 3, j = d & 7;
        int lanep = lk * 16 + l15;
        Mout[(long long)b * (CDIM * CDIM) + (((oc16 * 6 + ksg) << 6) + lanep) * 8 + j] =
            bfbits(acc);
    }
}

__global__ void zero_kernel(float* __restrict__ p, int n)
{
    for (int i = blockIdx.x * 256 + threadIdx.x; i < n; i += gridDim.x * 256) p[i] = 0.f;
}

// ---------------------------------------------------------------------------
// Workspace layout identical to R5-R8 (< 202 MB).
// ---------------------------------------------------------------------------
extern "C" void kernel_launch(void* const* d_in, const int* in_sizes, int n_in,
                              void* d_out, int out_size, void* d_ws, size_t ws_size,
                              hipStream_t stream)
{
    const float* x      = (const float*)d_in[0];
    const float* x_mask = (const float*)d_in[1];
    const float* temp   = (const float*)d_in[2];
    const float* q_w    = (const float*)d_in[3];
    const float* q_b    = (const float*)d_in[4];
    const float* qdw_w  = (const float*)d_in[5];
    const float* qdw_b  = (const float*)d_in[6];
    const float* kv_w   = (const float*)d_in[7];
    const float* kv_b   = (const float*)d_in[8];
    const float* kvdw_w = (const float*)d_in[9];
    const float* kvdw_b = (const float*)d_in[10];
    const float* newk_w = (const float*)d_in[11];
    const float* newk_b = (const float*)d_in[12];
    const float* newv_w = (const float*)d_in[13];
    const float* newv_b = (const float*)d_in[14];
    const float* proj_w = (const float*)d_in[15];
    const float* proj_b = (const float*)d_in[16];

    char* wsb = (char*)d_ws;
    bf16* A  = (bf16*)wsb;
    bf16* Bq = (bf16*)(wsb + 75497472);
    bf16* C  = (bf16*)(wsb + 150994944);
    unsigned short* qwb   = (unsigned short*)Bq;                    // 110,592
    unsigned short* nkb   = (unsigned short*)A + 25165824;          // 73,728
    unsigned short* nvb   = (unsigned short*)A + 25239552;          // 73,728
    unsigned short* Mbf   = (unsigned short*)A + 25313280;          // 147,456
    unsigned short* Wpack = (unsigned short*)C;                     // 663,552
    unsigned short* Xbf   = (unsigned short*)C + 663552;            // 12,582,912
    float* stats = (float*)(wsb + 201326592);
    float* ssq  = stats;                                            // 2304
    float* gram = ssq + 2304;                                       // 18432

    const long long N = NPIX;
    float* out = (float*)d_out;

    // stats zero + weight packs needed before S1
    zero_kernel<<<16, 256, 0, stream>>>(ssq, 2304 + 18432);
    pack_w1x1_kernel<<<432, 256, 0, stream>>>(q_w, qwb, 576, 192);
    pack_wconv_kernel<<<(384 * 9 * 192 + 255) / 256, 256, 0, stream>>>(kv_w, Wpack);

    // S1: qkv1 = conv1x1(x, q_w) : 192 -> 576 (fp32 in, bf16 out) -> A
    gemm1x1_allK_kernel<float, bf16, 192, 9, 200><<<dim3(256, 1, 4), 256, 0, stream>>>(
        x, 192 * N, x, 0, 192, qwb, 0, q_b, A, 576 * N);

    // S2: qkv = grouped 3x3 (groups=192, 3in/3out) -> B
    dwconv3x3_kernel<3, 3, 8><<<dim3(16, 192, 4), 256, 0, stream>>>(
        A, qdw_w, qdw_b, Bq, 192);

    // packs into A-tail (A dead after S2) + NHWC convert into C
    pack_w1x1_kernel<<<288, 256, 0, stream>>>(newk_w, nkb, 192, 384);
    pack_w1x1_kernel<<<288, 256, 0, stream>>>(newv_w, nvb, 192, 384);
    nchw2nhwc_kernel<<<dim3(256, 1, 4), 256, 0, stream>>>(x_mask, Xbf);

    // S3: kv1 = dense conv3x3(x_mask) 192->384 via MFMA -> A[0:25.17M)
    conv3x3_mfma_kernel<<<dim3(128, 6, 4), 256, 0, stream>>>(Xbf, Wpack, kv_b, A);

    // S4: kv2 = depthwise 3x3 (384 groups) -> C (overwrites Wpack/Xbf, done)
    dwconv3x3_kernel<1, 1, 16><<<dim3(8, 384, 4), 256, 0, stream>>>(
        A, kvdw_w, kvdw_b, C, 384);

    // S5: k_new / v_new = conv1x1 of concat (IC=384), MFMA -> A[0:25.17M)
    bf16* k_new = A;
    bf16* v_new = A + 12582912;
    gemm1x1_allK_kernel<bf16, bf16, 384, 3, 392><<<dim3(256, 1, 4), 256, 0, stream>>>(
        Bq + 192 * N, 576 * N, C, 384 * N, 192, nkb, 0, newk_b, k_new, 192 * N);
    gemm1x1_allK_kernel<bf16, bf16, 384, 3, 392><<<dim3(256, 1, 4), 256, 0, stream>>>(
        Bq + 384 * N, 576 * N, C + 192 * N, 384 * N, 192, nvb, 0, newv_b, v_new, 192 * N);

    // S6: sumsq(q,k,v) + Gram(q,k) via MFMA
    gram_mfma_kernel<<<dim3(32, 16), 256, 0, stream>>>(
        (const unsigned short*)Bq, 576 * N,
        (const unsigned short*)k_new, 192 * N,
        (const unsigned short*)v_new, 192 * N, ssq, gram);

    // S7: softmax + fold v-norm + proj -> per-batch M (bf16, packed layout)
    build_M_kernel<<<4, 256, 0, stream>>>(ssq, gram, temp, proj_w, Mbf);

    // S8: out = M_b @ v_new + proj_b (bf16 in, fp32 out)
    gemm1x1_allK_kernel<bf16, float, 192, 3, 200><<<dim3(256, 1, 4), 256, 0, stream>>>(
        v_new, 192 * N, v_new, 0, 192, Mbf, (long long)CDIM * CDIM, proj_b, out, 192 * N);
}